// Round 11
// baseline (313.085 us; speedup 1.0000x reference)
//
#include <hip/hip_runtime.h>
#include <math.h>

// ---------------------------------------------------------------------------
// GraphTransformerLayer N=50000, E=640000, D=128, H=8, DH=16  (gfx950)
// Round 22: R21 (best, 298.2us) + FFN1/FFN2 fused into k_ffn (512 thr):
//   u = relu(t1@W1s^T+badj) staged in LDS (64KB, stage-B frag layout),
//   then t2 = s*t1+b + u@W2^T from LDS. Kills the 51MB ub round-trip.
//   BN2 partial sums go straight to global atomics (same count as before);
//   sS/sB are per-thread float4 loads -> static LDS stays exactly 64KB.
// Everything else identical to R21 (fused h-cast/QKV, fp8 interleaved KV
// single-dword-gather attn, fat GEMMs, f16 residual + t2 frags).
//
// Fragment order for an MxK slab (M=128, K=KB*32):
//   elem index = ((kb*8 + mtile)*64 + lane)*8 + j
//   row = mtile*16 + (lane&15),  col = kb*32 + (lane>>4)*8 + j
// Swapped-operand MFMA: mfma(Wfrag, hfrag) -> C^T: row = m*16+(lane&15),
// cols = ntg*16+quad*4+{0..3} contiguous.
// ---------------------------------------------------------------------------

#define ND128 16384
typedef _Float16 f16;
typedef __attribute__((ext_vector_type(8))) _Float16 h8;
typedef __attribute__((ext_vector_type(4))) _Float16 h4;
typedef __attribute__((ext_vector_type(2))) _Float16 h2;
typedef __attribute__((ext_vector_type(4))) float f4;
typedef __attribute__((ext_vector_type(2))) float ff2;

__device__ __forceinline__ float fast_exp2(float x) {
#if __has_builtin(__builtin_amdgcn_exp2f)
    return __builtin_amdgcn_exp2f(x);
#else
    return exp2f(x);
#endif
}

template <int CTRL>
__device__ __forceinline__ float dppadd(float x) {
    int t = __builtin_amdgcn_update_dpp(0, __float_as_int(x), CTRL, 0xF, 0xF, false);
    return x + __int_as_float(t);
}
__device__ __forceinline__ float wsum8(float p) {
    p = dppadd<0xB1>(p);    // quad_perm [1,0,3,2]
    p = dppadd<0x4E>(p);    // quad_perm [2,3,0,1]
    p = dppadd<0x141>(p);   // row_half_mirror
    return p;
}

__device__ __forceinline__ ff2 fp8x2_dec_sw(unsigned v) {
    ff2 r;
    unsigned b0 = v & 0xffu, b1 = (v >> 8) & 0xffu;
    {
        unsigned e = (b0 >> 3) & 15u, m = b0 & 7u;
        float x = e ? __uint_as_float(((e + 120u) << 23) | (m << 20)) : (float)m * 0.001953125f;
        r.x = (b0 & 0x80u) ? -x : x;
    }
    {
        unsigned e = (b1 >> 3) & 15u, m = b1 & 7u;
        float x = e ? __uint_as_float(((e + 120u) << 23) | (m << 20)) : (float)m * 0.001953125f;
        r.y = (b1 & 0x80u) ? -x : x;
    }
    return r;
}

__device__ __forceinline__ ff2 dec_lo(unsigned v) {
#if __has_builtin(__builtin_amdgcn_cvt_pk_f32_fp8)
    return __builtin_amdgcn_cvt_pk_f32_fp8((int)v, false);
#else
    return fp8x2_dec_sw(v & 0xffffu);
#endif
}
__device__ __forceinline__ ff2 dec_hi(unsigned v) {
#if __has_builtin(__builtin_amdgcn_cvt_pk_f32_fp8)
    return __builtin_amdgcn_cvt_pk_f32_fp8((int)v, true);
#else
    return fp8x2_dec_sw((v >> 16) & 0xffffu);
#endif
}

#if !__has_builtin(__builtin_amdgcn_cvt_pk_fp8_f32)
__device__ __forceinline__ unsigned char fp8_1(float f) {
    float a = fabsf(f);
    unsigned sg = (__float_as_uint(f) >> 31) << 7;
    if (a >= 448.f) return (unsigned char)(sg | 0x7E);
    if (a < 0.0009765625f) return (unsigned char)sg;
    int E; float m = frexpf(a, &E);
    if (E - 1 < -6) {
        int q = (int)rintf(a * 512.f);
        if (q > 7) return (unsigned char)(sg | 0x08);
        return (unsigned char)(sg | q);
    }
    int q = (int)rintf(m * 16.f);
    if (q == 16) { q = 8; E += 1; }
    int Ef = E - 1 + 7;
    if (Ef > 15) return (unsigned char)(sg | 0x7E);
    return (unsigned char)(sg | (Ef << 3) | (q - 8));
}
#endif

__device__ __forceinline__ unsigned short fp8_pack2(float a0, float a1) {
#if __has_builtin(__builtin_amdgcn_cvt_pk_fp8_f32)
    int pk = __builtin_amdgcn_cvt_pk_fp8_f32(a0, a1, 0, false);
    return (unsigned short)(pk & 0xffff);
#else
    return (unsigned short)((unsigned)fp8_1(a0) | ((unsigned)fp8_1(a1) << 8));
#endif
}

// --- K1: hist (blocks [0,nhb)) UNION weight casts (blocks [nhb, nhb+6)). ---
__global__ __launch_bounds__(256) void k_prep_hist(
    const float* __restrict__ WQ, const float* __restrict__ WK,
    const float* __restrict__ WV, const float* __restrict__ WO,
    const float* __restrict__ W2,
    f16* __restrict__ Wqb, f16* __restrict__ Wkb,
    f16* __restrict__ Wvb, f16* __restrict__ Wob, f16* __restrict__ W2b,
    int* __restrict__ cursor, const int* __restrict__ dst,
    int N, int E, int nhb)
{
    const int tid = threadIdx.x;
    if (blockIdx.x < (unsigned)nhb) {
        int e = blockIdx.x * 256 + tid;
        if (e < E) atomicAdd(&cursor[dst[e]], 1);
        return;
    }
    const int ws = blockIdx.x - nhb;           // 0..5
    const float* Wsrc; f16* dstw; int K, base;
    if (ws < 4) {
        Wsrc = ws == 0 ? WQ : ws == 1 ? WK : ws == 2 ? WV : WO;
        dstw = ws == 0 ? Wqb : ws == 1 ? Wkb : ws == 2 ? Wvb : Wob;
        K = 128; base = 0;
    } else {
        Wsrc = W2; dstw = W2b; K = 256; base = (ws - 4) * 2048;
    }
#pragma unroll
    for (int it = 0; it < 8; ++it) {
        int cid = base + it * 256 + tid;
        int lane = cid & 63;
        int kb, nt;
        if (K == 128) { kb = (cid >> 6) & 3; nt = cid >> 8; }
        else          { kb = (cid >> 6) & 7; nt = cid >> 9; }
        int row = nt * 16 + (lane & 15);
        int col = kb * 32 + (lane >> 4) * 8;
        const float* pp = Wsrc + (size_t)row * K + col;
        f16 o8[8];
#pragma unroll
        for (int j = 0; j < 8; ++j) o8[j] = (f16)pp[j];
        *(h8*)(dstw + (size_t)cid * 8) = *(const h8*)o8;
    }
}

// --- K2: fused h-cast + QKV (512 thr). blocks [0,nsb) = scanA;
// blocks [nsb, nsb+slabs): stage h slab -> LDS+hb, then Q/K/V from LDS.
__global__ __launch_bounds__(512) void k_qkvf(
    const float* __restrict__ h, f16* __restrict__ hb,
    const f16* __restrict__ Wqb, const f16* __restrict__ Wkb,
    const f16* __restrict__ Wvb,
    f16* __restrict__ Qb, unsigned char* __restrict__ KV8,
    const int* __restrict__ cursor, int* __restrict__ bsum, int N, int nsb)
{
    __shared__ f16 sA[ND128];
    __shared__ int ws8[8];
    const int tid = threadIdx.x;
    if (blockIdx.x < (unsigned)nsb) {
        int base = blockIdx.x * 2048 + tid * 4;
        int s = 0;
#pragma unroll
        for (int j = 0; j < 4; ++j) {
            int idx = base + j;
            if (idx < N) s += cursor[idx];
        }
#pragma unroll
        for (int off = 32; off; off >>= 1) s += __shfl_down(s, off, 64);
        if ((tid & 63) == 0) ws8[tid >> 6] = s;
        __syncthreads();
        if (tid == 0) {
            int r = 0;
#pragma unroll
            for (int k = 0; k < 8; ++k) r += ws8[k];
            bsum[blockIdx.x] = r;
        }
        return;
    }
    const int slab = blockIdx.x - nsb;
#pragma unroll
    for (int it = 0; it < 4; ++it) {
        int cid = it * 512 + tid;              // 0..2047
        int lane = cid & 63;
        int m = (cid >> 6) & 7;
        int kb = cid >> 9;
        int row = slab * 128 + m * 16 + (lane & 15);
        int col = kb * 32 + (lane >> 4) * 8;
        f16 o8[8];
        if (row < N) {
            const float* pp = h + (size_t)row * 128 + col;
            float4 f0 = *(const float4*)pp;
            float4 f1 = *(const float4*)(pp + 4);
            o8[0] = (f16)f0.x; o8[1] = (f16)f0.y; o8[2] = (f16)f0.z; o8[3] = (f16)f0.w;
            o8[4] = (f16)f1.x; o8[5] = (f16)f1.y; o8[6] = (f16)f1.z; o8[7] = (f16)f1.w;
        } else {
#pragma unroll
            for (int j = 0; j < 8; ++j) o8[j] = (f16)0.f;
        }
        h8 v = *(const h8*)o8;
        *(h8*)(hb + (size_t)slab * ND128 + (size_t)cid * 8) = v;
        *(h8*)(sA + (size_t)cid * 8) = v;
    }
    __syncthreads();

    const int w2 = tid >> 6, lane = tid & 63;   // w2 = global nt index 0..7
    const int rl = lane & 15, quad = lane >> 4;
#pragma unroll
    for (int oidx = 0; oidx < 3; ++oidx) {
        const f16* __restrict__ Wb = oidx == 0 ? Wqb : oidx == 1 ? Wkb : Wvb;
        h8 bfr[4];
#pragma unroll
        for (int kb = 0; kb < 4; ++kb)
            bfr[kb] = *(const h8*)(Wb + (size_t)((w2 * 4 + kb) * 64 + lane) * 8);

        f4 acc[8];
        f4 zero = {0.f, 0.f, 0.f, 0.f};
#pragma unroll
        for (int m = 0; m < 8; ++m) acc[m] = zero;
#pragma unroll
        for (int m = 0; m < 8; ++m) {
#pragma unroll
            for (int kb = 0; kb < 4; ++kb) {
                h8 a = *(const h8*)(sA + (size_t)((kb * 8 + m) * 64 + lane) * 8);
                acc[m] = __builtin_amdgcn_mfma_f32_16x16x32_f16(bfr[kb], a, acc[m], 0, 0, 0);
            }
        }
        if (oidx == 0) {
#pragma unroll
            for (int m = 0; m < 8; ++m) {
                int gr = slab * 128 + m * 16 + rl;
                if (gr < N) {
                    h4 o;
                    o[0] = (f16)acc[m][0]; o[1] = (f16)acc[m][1];
                    o[2] = (f16)acc[m][2]; o[3] = (f16)acc[m][3];
                    *(h4*)(Qb + (size_t)gr * 128 + w2 * 16 + quad * 4) = o;
                }
            }
        } else {
            const int koff = (oidx == 2) ? 2 : 0;  // K -> bytes 0-1, V -> 2-3
#pragma unroll
            for (int m = 0; m < 8; ++m) {
                int gr = slab * 128 + m * 16 + rl;
                if (gr < N) {
                    int c0 = w2 * 16 + quad * 4;
                    unsigned short p01 = fp8_pack2(acc[m][0], acc[m][1]);
                    unsigned short p23 = fp8_pack2(acc[m][2], acc[m][3]);
                    unsigned char* rowp = KV8 + (size_t)gr * 256 + (size_t)c0 * 2 + koff;
                    *(unsigned short*)(rowp) = p01;
                    *(unsigned short*)(rowp + 4) = p23;
                }
            }
        }
    }
}

// --- scan part C ----------------------------------------------------------
__global__ __launch_bounds__(256) void k_scanC(
    const int* __restrict__ cnt, const int* __restrict__ bsum,
    int* __restrict__ rowptr, int* __restrict__ cursor, int N, int nsb)
{
    const int t = threadIdx.x, b = blockIdx.x;
    __shared__ int sboff;
    if (t == 0) {
        int r = 0;
        for (int i2 = 0; i2 < b; ++i2) r += bsum[i2];
        sboff = r;
    }
    if (t == 64 && b == nsb - 1) {
        int r = 0;
        for (int i2 = 0; i2 < nsb; ++i2) r += bsum[i2];
        rowptr[N] = r;
    }
    int base = b * 2048 + t * 8;
    int loc[8];
    int s = 0;
#pragma unroll
    for (int j = 0; j < 8; ++j) {
        int idx = base + j;
        loc[j] = (idx < N) ? cnt[idx] : 0;
        s += loc[j];
    }
    __shared__ int part[256];
    part[t] = s;
    __syncthreads();
    for (int off = 1; off < 256; off <<= 1) {
        int v = (t >= off) ? part[t - off] : 0;
        __syncthreads();
        part[t] += v;
        __syncthreads();
    }
    int run = sboff + (t ? part[t - 1] : 0);
#pragma unroll
    for (int j = 0; j < 8; ++j) {
        int idx = base + j;
        if (idx < N) { rowptr[idx] = run; cursor[idx] = run; run += loc[j]; }
    }
}

// --- scatter edges into CSR ------------------------------------------------
__global__ __launch_bounds__(256) void k_scatter(
    const int* __restrict__ src, const int* __restrict__ dst,
    int* __restrict__ cursor, int* __restrict__ csr_src, int E)
{
    int e = blockIdx.x * 256 + threadIdx.x;
    if (e < E) {
        int pos = atomicAdd(&cursor[dst[e]], 1);
        csr_src[pos] = src[e];
    }
}

// --- attention: one wave per node, lane owns channels (2l, 2l+1). ----------
// ONE dword gather per edge: dec_lo -> K pair, dec_hi -> V pair.
__global__ __launch_bounds__(256) void k_attn(
    const f16* __restrict__ Qb, const unsigned char* __restrict__ KV8,
    const int* __restrict__ rowptr, const int* __restrict__ csr_src,
    f16* __restrict__ attnf, int N)
{
    const int node = blockIdx.x * 4 + (threadIdx.x >> 6);
    const int lane = threadIdx.x & 63;
    if (node >= N) return;
    const int beg = rowptr[node], end = rowptr[node + 1];

    float qx, qy;
    {
        h2 q2 = ((const h2*)(Qb + (size_t)node * 128))[lane];
        const float SCL = 0.25f * 1.44269504f;
        qx = (float)q2[0] * SCL;
        qy = (float)q2[1] * SCL;
    }
    const float CLP = 5.f * 1.44269504f;
    const unsigned loff = 4u * (unsigned)lane;

    float axA = 0.f, ayA = 0.f, axB = 0.f, ayB = 0.f, zA = 0.f, zB = 0.f;
    int i = beg;
    for (; i + 7 < end; i += 8) {
        int s[8];
#pragma unroll
        for (int u = 0; u < 8; ++u) s[u] = csr_src[i + u];
        unsigned kv[8];
#pragma unroll
        for (int u = 0; u < 8; ++u)
            kv[u] = *(const unsigned*)(KV8 + (size_t)s[u] * 256 + loff);
        float p[8];
#pragma unroll
        for (int u = 0; u < 8; ++u) {
            ff2 kf = dec_lo(kv[u]);
            p[u] = fmaf(qx, kf.x, qy * kf.y);
        }
#pragma unroll
        for (int u = 0; u < 8; ++u) p[u] = wsum8(p[u]);
        float sc[8];
#pragma unroll
        for (int u = 0; u < 8; ++u)
            sc[u] = fast_exp2(fminf(fmaxf(p[u], -CLP), CLP));
#pragma unroll
        for (int u = 0; u < 8; ++u) {
            ff2 vf = dec_hi(kv[u]);
            if (u & 1) {
                axB = fmaf(vf.x, sc[u], axB); ayB = fmaf(vf.y, sc[u], ayB); zB += sc[u];
            } else {
                axA = fmaf(vf.x, sc[u], axA); ayA = fmaf(vf.y, sc[u], ayA); zA += sc[u];
            }
        }
    }
    if (i + 3 < end) {
        int s[4];
#pragma unroll
        for (int u = 0; u < 4; ++u) s[u] = csr_src[i + u];
        unsigned kv[4];
#pragma unroll
        for (int u = 0; u < 4; ++u)
            kv[u] = *(const unsigned*)(KV8 + (size_t)s[u] * 256 + loff);
#pragma unroll
        for (int u = 0; u < 4; ++u) {
            ff2 kf = dec_lo(kv[u]);
            float p = wsum8(fmaf(qx, kf.x, qy * kf.y));
            float scu = fast_exp2(fminf(fmaxf(p, -CLP), CLP));
            ff2 vf = dec_hi(kv[u]);
            if (u & 1) {
                axB = fmaf(vf.x, scu, axB); ayB = fmaf(vf.y, scu, ayB); zB += scu;
            } else {
                axA = fmaf(vf.x, scu, axA); ayA = fmaf(vf.y, scu, ayA); zA += scu;
            }
        }
        i += 4;
    }
    for (; i < end; ++i) {
        int s0 = csr_src[i];
        unsigned kv = *(const unsigned*)(KV8 + (size_t)s0 * 256 + loff);
        ff2 kf = dec_lo(kv);
        float p0 = wsum8(fmaf(qx, kf.x, qy * kf.y));
        float sc0 = fast_exp2(fminf(fmaxf(p0, -CLP), CLP));
        ff2 vf = dec_hi(kv);
        axA = fmaf(vf.x, sc0, axA); ayA = fmaf(vf.y, sc0, ayA);
        zA += sc0;
    }
    float inv = 1.f / (zA + zB);
    h2 o2;
    o2[0] = (f16)((axA + axB) * inv);
    o2[1] = (f16)((ayA + ayB) * inv);
    int slab = node >> 7, m = (node >> 4) & 7, lr = node & 15;
    int kb = lane >> 4, quad2 = (lane & 15) >> 2, j = (lane & 3) * 2;
    *(h2*)(attnf + (size_t)slab * ND128 +
           (size_t)(((kb * 8 + m) * 64 + lr + 16 * quad2) * 8 + j)) = o2;
}

// --- O-proj (FAT): t1 = attn @ WO^T + h + bO -> f16 frag t1b; BN1 sums. ----
__global__ __launch_bounds__(256) void k_oproj(
    const f16* __restrict__ attnf, const f16* __restrict__ Wob,
    const f16* __restrict__ hbf, const float* __restrict__ bO,
    f16* __restrict__ t1b, float* __restrict__ bn, int N)
{
    __shared__ float csum[128], csq[128];
    const int tid = threadIdx.x, slab = blockIdx.x;
    const int w = tid >> 6, lane = tid & 63;
    if (tid < 128) { csum[tid] = 0.f; csq[tid] = 0.f; }
    __syncthreads();
    const f16* A = attnf + (size_t)slab * ND128;
    const f16* HB = hbf + (size_t)slab * ND128;

    h8 bfr[2][4];
#pragma unroll
    for (int nt = 0; nt < 2; ++nt)
#pragma unroll
        for (int kb = 0; kb < 4; ++kb)
            bfr[nt][kb] = *(const h8*)(Wob + (size_t)(((2 * w + nt) * 4 + kb) * 64 + lane) * 8);

    f4 acc[8][2];
    f4 zero = {0.f, 0.f, 0.f, 0.f};
#pragma unroll
    for (int m = 0; m < 8; ++m) { acc[m][0] = zero; acc[m][1] = zero; }
#pragma unroll
    for (int m = 0; m < 8; ++m) {
#pragma unroll
        for (int kb = 0; kb < 4; ++kb) {
            h8 a = *(const h8*)(A + (size_t)((kb * 8 + m) * 64 + lane) * 8);
            acc[m][0] = __builtin_amdgcn_mfma_f32_16x16x32_f16(bfr[0][kb], a, acc[m][0], 0, 0, 0);
            acc[m][1] = __builtin_amdgcn_mfma_f32_16x16x32_f16(bfr[1][kb], a, acc[m][1], 0, 0, 0);
        }
    }

    const int rl = lane & 15, quad = lane >> 4;
    float4 bo[2];
#pragma unroll
    for (int nt = 0; nt < 2; ++nt)
        bo[nt] = *(const float4*)(bO + w * 32 + nt * 16 + quad * 4);
    float pcs[2][4], pcq[2][4];
#pragma unroll
    for (int nt = 0; nt < 2; ++nt)
#pragma unroll
        for (int r = 0; r < 4; ++r) { pcs[nt][r] = 0.f; pcq[nt][r] = 0.f; }

#pragma unroll
    for (int m = 0; m < 8; ++m) {
        int gr = slab * 128 + m * 16 + rl;
        if (gr < N) {
#pragma unroll
            for (int nt = 0; nt < 2; ++nt) {
                size_t fidx = (size_t)(((w * 8 + m) * 64 + (nt * 2 + (quad >> 1)) * 16 + rl) * 8 +
                                       (quad & 1) * 4);
                h4 hv4 = *(const h4*)(HB + fidx);
                float v0 = acc[m][nt][0] + (float)hv4[0] + bo[nt].x;
                float v1 = acc[m][nt][1] + (float)hv4[1] + bo[nt].y;
                float v2 = acc[m][nt][2] + (float)hv4[2] + bo[nt].z;
                float v3 = acc[m][nt][3] + (float)hv4[3] + bo[nt].w;
                h4 o; o[0] = (f16)v0; o[1] = (f16)v1; o[2] = (f16)v2; o[3] = (f16)v3;
                *(h4*)(t1b + (size_t)slab * ND128 + fidx) = o;
                pcs[nt][0] += v0; pcq[nt][0] += v0 * v0;
                pcs[nt][1] += v1; pcq[nt][1] += v1 * v1;
                pcs[nt][2] += v2; pcq[nt][2] += v2 * v2;
                pcs[nt][3] += v3; pcq[nt][3] += v3 * v3;
            }
        }
    }
#pragma unroll
    for (int nt = 0; nt < 2; ++nt)
#pragma unroll
        for (int r = 0; r < 4; ++r) {
            float s = pcs[nt][r], q = pcq[nt][r];
            s += __shfl_xor(s, 8, 16); q += __shfl_xor(q, 8, 16);
            s += __shfl_xor(s, 4, 16); q += __shfl_xor(q, 4, 16);
            s += __shfl_xor(s, 2, 16); q += __shfl_xor(q, 2, 16);
            s += __shfl_xor(s, 1, 16); q += __shfl_xor(q, 1, 16);
            if (rl == 0) {
                int cl = w * 32 + nt * 16 + quad * 4 + r;
                atomicAdd(&csum[cl], s);
                atomicAdd(&csq[cl], q);
            }
        }
    __syncthreads();
    if (tid < 128) {
        atomicAdd(bn + tid, csum[tid]);
        atomicAdd(bn + 128 + tid, csq[tid]);
    }
}

// --- fold BN1 into W1/bias. 256 blocks (one per W1 row). -------------------
__global__ __launch_bounds__(128) void k_fold1(
    const float* __restrict__ bn, const float* __restrict__ g1,
    const float* __restrict__ bb1, const float* __restrict__ W1,
    const float* __restrict__ b1, f16* __restrict__ W1b,
    float* __restrict__ badj, float* __restrict__ sfold,
    float* __restrict__ bfold, int N)
{
    const int o = blockIdx.x, i = threadIdx.x;
    float invN = 1.f / (float)N;
    float mu = bn[i] * invN;
    float var = bn[128 + i] * invN - mu * mu;
    float s = g1[i] * rsqrtf(var + 1e-5f);
    float bb = bb1[i] - mu * s;
    if (o == 0) { sfold[i] = s; bfold[i] = bb; }
    float wv = W1[(size_t)o * 128 + i];
    __shared__ float red[128];
    red[i] = wv * bb;
    const int nt = o >> 4, lanelow = o & 15;
    const int kb = i >> 5, quad = (i >> 3) & 3, j = i & 7;
    W1b[(size_t)(((nt * 4 + kb) * 64 + lanelow + 16 * quad) * 8 + j)] = (f16)(wv * s);
    __syncthreads();
#pragma unroll
    for (int off = 64; off; off >>= 1) {
        if (i < off) red[i] += red[i + off];
        __syncthreads();
    }
    if (i == 0) badj[o] = b1[o] + red[0];
}

// --- fused FFN (512 thr, one block per slab): ------------------------------
// stage A: u = relu(t1 @ W1s^T + badj) -> uf LDS (64KB, K=256 frag layout)
// stage B: t2 = (s1*t1 + b1v + b2) + u @ W2^T -> f16 frag t2f; BN2 sums.
__global__ __launch_bounds__(512) void k_ffn(
    const f16* __restrict__ t1b, const f16* __restrict__ W1b,
    const float* __restrict__ badj, const f16* __restrict__ W2b,
    const float* __restrict__ sfold, const float* __restrict__ bfold,
    const float* __restrict__ b2, f16* __restrict__ t2f,
    float* __restrict__ bn, int N)
{
    __shared__ f16 uf[32768];              // exactly 64 KB
    const int tid = threadIdx.x, slab = blockIdx.x;
    const int w2 = tid >> 6, lane = tid & 63;
    const int rl = lane & 15, quad = lane >> 4;
    const f16* T1 = t1b + (size_t)slab * ND128;

    // ---- stage A: 8 waves x 2 ntg -> 256 channels of u into LDS ----
    {
        h8 bfr[2][4];
#pragma unroll
        for (int nt = 0; nt < 2; ++nt) {
            int ntg = w2 * 2 + nt;
#pragma unroll
            for (int kb = 0; kb < 4; ++kb)
                bfr[nt][kb] = *(const h8*)(W1b + (size_t)((ntg * 4 + kb) * 64 + lane) * 8);
        }
        f4 acc[8][2];
        f4 zero = {0.f, 0.f, 0.f, 0.f};
#pragma unroll
        for (int m = 0; m < 8; ++m) { acc[m][0] = zero; acc[m][1] = zero; }
#pragma unroll
        for (int m = 0; m < 8; ++m) {
#pragma unroll
            for (int kb = 0; kb < 4; ++kb) {
                h8 a = *(const h8*)(T1 + (size_t)((kb * 8 + m) * 64 + lane) * 8);
                acc[m][0] = __builtin_amdgcn_mfma_f32_16x16x32_f16(bfr[0][kb], a, acc[m][0], 0, 0, 0);
                acc[m][1] = __builtin_amdgcn_mfma_f32_16x16x32_f16(bfr[1][kb], a, acc[m][1], 0, 0, 0);
            }
        }
        float4 ba[2];
#pragma unroll
        for (int nt = 0; nt < 2; ++nt)
            ba[nt] = *(const float4*)(badj + (w2 * 2 + nt) * 16 + quad * 4);
#pragma unroll
        for (int m = 0; m < 8; ++m) {
#pragma unroll
            for (int nt = 0; nt < 2; ++nt) {
                h4 o;
                o[0] = (f16)fmaxf(acc[m][nt][0] + ba[nt].x, 0.f);
                o[1] = (f16)fmaxf(acc[m][nt][1] + ba[nt].y, 0.f);
                o[2] = (f16)fmaxf(acc[m][nt][2] + ba[nt].z, 0.f);
                o[3] = (f16)fmaxf(acc[m][nt][3] + ba[nt].w, 0.f);
                // channel c0 = (w2*2+nt)*16 + quad*4; kbu = w2
                *(h4*)(uf + (size_t)(((w2 * 8 + m) * 64 +
                       (nt * 2 + (quad >> 1)) * 16 + rl) * 8 + (quad & 1) * 4)) = o;
            }
        }
    }
    __syncthreads();

    // ---- stage B: 8 waves x 1 ntg -> 128 channels of t2 ----
    {
        h8 bfr2[8];
#pragma unroll
        for (int kb = 0; kb < 8; ++kb)
            bfr2[kb] = *(const h8*)(W2b + (size_t)((w2 * 8 + kb) * 64 + lane) * 8);

        f4 acc2[8];
        f4 zero = {0.f, 0.f, 0.f, 0.f};
#pragma unroll
        for (int m = 0; m < 8; ++m) acc2[m] = zero;
#pragma unroll
        for (int m = 0; m < 8; ++m) {
#pragma unroll
            for (int kb = 0; kb < 8; ++kb) {
                h8 a = *(const h8*)(uf + (size_t)((kb * 8 + m) * 64 + lane) * 8);
                acc2[m] = __builtin_amdgcn_mfma_f32_16x16x32_f16(bfr2[kb], a, acc2[m], 0, 0, 0);
            }
        }

        const int c0 = w2 * 16 + quad * 4;
        float4 ss = *(const float4*)(sfold + c0);
        float4 sbA = *(const float4*)(bfold + c0);
        float4 sbB = *(const float4*)(b2 + c0);
        float4 sb;
        sb.x = sbA.x + sbB.x; sb.y = sbA.y + sbB.y;
        sb.z = sbA.z + sbB.z; sb.w = sbA.w + sbB.w;

        float pcs[4] = {0.f, 0.f, 0.f, 0.f};
        float pcq[4] = {0.f, 0.f, 0.f, 0.f};
#pragma unroll
        for (int m = 0; m < 8; ++m) {
            int gr = slab * 128 + m * 16 + rl;
            if (gr < N) {
                size_t fidx = (size_t)((((w2 >> 1) * 8 + m) * 64 +
                              ((w2 & 1) * 2 + (quad >> 1)) * 16 + rl) * 8 + (quad & 1) * 4);
                h4 t1v = *(const h4*)(T1 + fidx);
                h4 o2;
                o2[0] = (f16)(acc2[m][0] + fmaf(ss.x, (float)t1v[0], sb.x));
                o2[1] = (f16)(acc2[m][1] + fmaf(ss.y, (float)t1v[1], sb.y));
                o2[2] = (f16)(acc2[m][2] + fmaf(ss.z, (float)t1v[2], sb.z));
                o2[3] = (f16)(acc2[m][3] + fmaf(ss.w, (float)t1v[3], sb.w));
                *(h4*)(t2f + (size_t)slab * ND128 + fidx) = o2;
                float r0 = (float)o2[0], r1 = (float)o2[1];
                float r2 = (float)o2[2], r3 = (float)o2[3];
                pcs[0] += r0; pcq[0] += r0 * r0;
                pcs[1] += r1; pcq[1] += r1 * r1;
                pcs[2] += r2; pcq[2] += r2 * r2;
                pcs[3] += r3; pcq[3] += r3 * r3;
            }
        }
#pragma unroll
        for (int r = 0; r < 4; ++r) {
            float s = pcs[r], q = pcq[r];
            s += __shfl_xor(s, 8, 16); q += __shfl_xor(q, 8, 16);
            s += __shfl_xor(s, 4, 16); q += __shfl_xor(q, 4, 16);
            s += __shfl_xor(s, 2, 16); q += __shfl_xor(q, 2, 16);
            s += __shfl_xor(s, 1, 16); q += __shfl_xor(q, 1, 16);
            if (rl == 0) {
                int cl = c0 + r;
                atomicAdd(bn + 256 + cl, s);
                atomicAdd(bn + 384 + cl, q);
            }
        }
    }
}

// --- BN2: read f16 t2 frags, normalize, write fp32 rows (coalesced). -------
__global__ __launch_bounds__(256) void k_bn2(
    const f16* __restrict__ t2f, float* __restrict__ out,
    const float* __restrict__ bn,
    const float* __restrict__ g2, const float* __restrict__ bb2, int N)
{
    __shared__ float sS[128], sB[128];
    const int tid = threadIdx.x;
    if (tid < 128) {
        float invN = 1.f / (float)N;
        float mu = bn[256 + tid] * invN;
        float var = bn[384 + tid] * invN - mu * mu;
        float scl = g2[tid] * rsqrtf(var + 1e-5f);
        sS[tid] = scl;
        sB[tid] = bb2[tid] - mu * scl;
    }
    __syncthreads();
    size_t idx = (size_t)blockIdx.x * 256 + tid;   // h4-group index
    size_t total = (size_t)N * 32;
    if (idx < total) {
        int gr = (int)(idx >> 5);
        int c0 = ((int)idx & 31) * 4;
        int slab = gr >> 7, m = (gr >> 4) & 7, rl = gr & 15;
        int w = c0 >> 5, nt = (c0 >> 4) & 1, q = (c0 >> 2) & 3;
        size_t fidx = (size_t)(((w * 8 + m) * 64 + (nt * 2 + (q >> 1)) * 16 + rl) * 8 +
                               (q & 1) * 4);
        h4 v = *(const h4*)(t2f + (size_t)slab * ND128 + fidx);
        float4 o;
        o.x = fmaf((float)v[0], sS[c0 + 0], sB[c0 + 0]);
        o.y = fmaf((float)v[1], sS[c0 + 1], sB[c0 + 1]);
        o.z = fmaf((float)v[2], sS[c0 + 2], sB[c0 + 2]);
        o.w = fmaf((float)v[3], sS[c0 + 3], sB[c0 + 3]);
        *(float4*)(out + (size_t)gr * 128 + c0) = o;
    }
}

extern "C" void kernel_launch(void* const* d_in, const int* in_sizes, int n_in,
                              void* d_out, int out_size, void* d_ws, size_t ws_size,
                              hipStream_t stream)
{
    const float* h   = (const float*)d_in[0];
    const int*   src = (const int*)d_in[1];
    const int*   dst = (const int*)d_in[2];
    const float* WQ  = (const float*)d_in[3];
    const float* WK  = (const float*)d_in[4];
    const float* WV  = (const float*)d_in[5];
    const float* WO  = (const float*)d_in[6];
    const float* bO  = (const float*)d_in[7];
    const float* W1  = (const float*)d_in[8];
    const float* b1  = (const float*)d_in[9];
    const float* W2  = (const float*)d_in[10];
    const float* b2  = (const float*)d_in[11];
    const float* g1  = (const float*)d_in[12];
    const float* bb1 = (const float*)d_in[13];
    const float* g2  = (const float*)d_in[14];
    const float* bb2 = (const float*)d_in[15];
    float* out = (float*)d_out;

    int N = in_sizes[0] / 128;
    int E = in_sizes[1];
    int slabs = (N + 127) / 128;
    int nsb = (N + 2047) / 2048;               // scan blocks (~25)
    int nhb = (E + 255) / 256;                 // edge blocks (~2500)
    const size_t B1 = (size_t)slabs * 32768;   // bytes of one f16 N_pad x 128 buffer

    char* Wp = (char*)d_ws;
    f16* hb  = (f16*)Wp;                       // h f16 frags, lives through oproj
    f16* Qb  = (f16*)(Wp + B1);                // B1
    unsigned char* KV8 = (unsigned char*)(Wp + 2 * B1);  // B1 (fp8 K|V interleaved words)
    f16* attnf = (f16*)(Wp + 3 * B1);          // B1; becomes t2f after ffn
    f16* t1b = (f16*)(Wp + 4 * B1);            // B1
    f16* t2f = attnf;                          // attnf dead after oproj
    const size_t base = 5 * B1;
    f16* Wqb = (f16*)(Wp + base);
    f16* Wkb = (f16*)(Wp + base + 32768);
    f16* Wvb = (f16*)(Wp + base + 65536);
    f16* Wob = (f16*)(Wp + base + 98304);
    f16* W1b = (f16*)(Wp + base + 131072);
    f16* W2b = (f16*)(Wp + base + 196608);
    float* badj  = (float*)(Wp + base + 262144);
    float* sfold = (float*)(Wp + base + 263168);
    float* bfold = (float*)(Wp + base + 263680);
    float* bn    = (float*)(Wp + base + 264192);     // 512 floats (memset)
    int* bsum    = (int*)(Wp + base + 266240);       // 64 ints (memset)
    int* cursor  = (int*)(Wp + base + 266496);       // N ints (memset)
    int* rowptr  = (int*)(Wp + base + 266496 + (size_t)N * 4);
    int* csr     = (int*)(Wp + base + 266496 + (size_t)N * 8 + 8);

    // zero bn(2048) + bsum(256) + cursor(N*4) in one memset
    hipMemsetAsync(Wp + base + 264192, 0, 2304 + (size_t)N * 4, stream);
    k_prep_hist<<<nhb + 6, 256, 0, stream>>>(
        WQ, WK, WV, WO, W2, Wqb, Wkb, Wvb, Wob, W2b, cursor, dst, N, E, nhb);
    k_qkvf<<<nsb + slabs, 512, 0, stream>>>(
        h, hb, Wqb, Wkb, Wvb, Qb, KV8, cursor, bsum, N, nsb);
    k_scanC<<<nsb, 256, 0, stream>>>(cursor, bsum, rowptr, cursor, N, nsb);
    k_scatter<<<nhb, 256, 0, stream>>>(src, dst, cursor, csr, E);
    k_attn<<<(N + 3) / 4, 256, 0, stream>>>(Qb, KV8, rowptr, csr, attnf, N);
    k_oproj<<<slabs, 256, 0, stream>>>(attnf, Wob, hb, bO, t1b, bn, N);
    k_fold1<<<256, 128, 0, stream>>>(bn, g1, bb1, W1, b1, W1b, badj, sfold, bfold, N);
    k_ffn<<<slabs, 512, 0, stream>>>(t1b, W1b, badj, W2b, sfold, bfold, b2, t2f, bn, N);
    k_bn2<<<(int)(((size_t)N * 32 + 255) / 256), 256, 0, stream>>>(t2f, out, bn, g2, bb2, N);
}

// Round 12
// 299.861 us; speedup vs baseline: 1.0441x; 1.0441x over previous
//
#include <hip/hip_runtime.h>
#include <math.h>

// ---------------------------------------------------------------------------
// GraphTransformerLayer N=50000, E=640000, D=128, H=8, DH=16  (gfx950)
// Round 23: revert R22's FFN fusion (occupancy collapse: 391x512 blocks,
// 64KB LDS -> 1.5 blocks/CU, 18.5% occ, 52.8us). Back to R21 split FFN
// (298.2us best). One change: k_attn main loop gets a 2-stage cross-chunk
// software pipeline (prefetch next 8 csr+KV gathers during compute ->
// 16 outstanding loads instead of 8).
//
// Fragment order for an MxK slab (M=128, K=KB*32):
//   elem index = ((kb*8 + mtile)*64 + lane)*8 + j
//   row = mtile*16 + (lane&15),  col = kb*32 + (lane>>4)*8 + j
// Swapped-operand MFMA: mfma(Wfrag, hfrag) -> C^T: row = m*16+(lane&15),
// cols = ntg*16+quad*4+{0..3} contiguous.
// ---------------------------------------------------------------------------

#define ND128 16384
typedef _Float16 f16;
typedef __attribute__((ext_vector_type(8))) _Float16 h8;
typedef __attribute__((ext_vector_type(4))) _Float16 h4;
typedef __attribute__((ext_vector_type(2))) _Float16 h2;
typedef __attribute__((ext_vector_type(4))) float f4;
typedef __attribute__((ext_vector_type(2))) float ff2;

__device__ __forceinline__ float fast_exp2(float x) {
#if __has_builtin(__builtin_amdgcn_exp2f)
    return __builtin_amdgcn_exp2f(x);
#else
    return exp2f(x);
#endif
}

template <int CTRL>
__device__ __forceinline__ float dppadd(float x) {
    int t = __builtin_amdgcn_update_dpp(0, __float_as_int(x), CTRL, 0xF, 0xF, false);
    return x + __int_as_float(t);
}
__device__ __forceinline__ float wsum8(float p) {
    p = dppadd<0xB1>(p);    // quad_perm [1,0,3,2]
    p = dppadd<0x4E>(p);    // quad_perm [2,3,0,1]
    p = dppadd<0x141>(p);   // row_half_mirror
    return p;
}

__device__ __forceinline__ ff2 fp8x2_dec_sw(unsigned v) {
    ff2 r;
    unsigned b0 = v & 0xffu, b1 = (v >> 8) & 0xffu;
    {
        unsigned e = (b0 >> 3) & 15u, m = b0 & 7u;
        float x = e ? __uint_as_float(((e + 120u) << 23) | (m << 20)) : (float)m * 0.001953125f;
        r.x = (b0 & 0x80u) ? -x : x;
    }
    {
        unsigned e = (b1 >> 3) & 15u, m = b1 & 7u;
        float x = e ? __uint_as_float(((e + 120u) << 23) | (m << 20)) : (float)m * 0.001953125f;
        r.y = (b1 & 0x80u) ? -x : x;
    }
    return r;
}

__device__ __forceinline__ ff2 dec_lo(unsigned v) {
#if __has_builtin(__builtin_amdgcn_cvt_pk_f32_fp8)
    return __builtin_amdgcn_cvt_pk_f32_fp8((int)v, false);
#else
    return fp8x2_dec_sw(v & 0xffffu);
#endif
}
__device__ __forceinline__ ff2 dec_hi(unsigned v) {
#if __has_builtin(__builtin_amdgcn_cvt_pk_f32_fp8)
    return __builtin_amdgcn_cvt_pk_f32_fp8((int)v, true);
#else
    return fp8x2_dec_sw((v >> 16) & 0xffffu);
#endif
}

#if !__has_builtin(__builtin_amdgcn_cvt_pk_fp8_f32)
__device__ __forceinline__ unsigned char fp8_1(float f) {
    float a = fabsf(f);
    unsigned sg = (__float_as_uint(f) >> 31) << 7;
    if (a >= 448.f) return (unsigned char)(sg | 0x7E);
    if (a < 0.0009765625f) return (unsigned char)sg;
    int E; float m = frexpf(a, &E);
    if (E - 1 < -6) {
        int q = (int)rintf(a * 512.f);
        if (q > 7) return (unsigned char)(sg | 0x08);
        return (unsigned char)(sg | q);
    }
    int q = (int)rintf(m * 16.f);
    if (q == 16) { q = 8; E += 1; }
    int Ef = E - 1 + 7;
    if (Ef > 15) return (unsigned char)(sg | 0x7E);
    return (unsigned char)(sg | (Ef << 3) | (q - 8));
}
#endif

__device__ __forceinline__ unsigned short fp8_pack2(float a0, float a1) {
#if __has_builtin(__builtin_amdgcn_cvt_pk_fp8_f32)
    int pk = __builtin_amdgcn_cvt_pk_fp8_f32(a0, a1, 0, false);
    return (unsigned short)(pk & 0xffff);
#else
    return (unsigned short)((unsigned)fp8_1(a0) | ((unsigned)fp8_1(a1) << 8));
#endif
}

// --- K1: hist (blocks [0,nhb)) UNION weight casts (blocks [nhb, nhb+6)). ---
__global__ __launch_bounds__(256) void k_prep_hist(
    const float* __restrict__ WQ, const float* __restrict__ WK,
    const float* __restrict__ WV, const float* __restrict__ WO,
    const float* __restrict__ W2,
    f16* __restrict__ Wqb, f16* __restrict__ Wkb,
    f16* __restrict__ Wvb, f16* __restrict__ Wob, f16* __restrict__ W2b,
    int* __restrict__ cursor, const int* __restrict__ dst,
    int N, int E, int nhb)
{
    const int tid = threadIdx.x;
    if (blockIdx.x < (unsigned)nhb) {
        int e = blockIdx.x * 256 + tid;
        if (e < E) atomicAdd(&cursor[dst[e]], 1);
        return;
    }
    const int ws = blockIdx.x - nhb;           // 0..5
    const float* Wsrc; f16* dstw; int K, base;
    if (ws < 4) {
        Wsrc = ws == 0 ? WQ : ws == 1 ? WK : ws == 2 ? WV : WO;
        dstw = ws == 0 ? Wqb : ws == 1 ? Wkb : ws == 2 ? Wvb : Wob;
        K = 128; base = 0;
    } else {
        Wsrc = W2; dstw = W2b; K = 256; base = (ws - 4) * 2048;
    }
#pragma unroll
    for (int it = 0; it < 8; ++it) {
        int cid = base + it * 256 + tid;
        int lane = cid & 63;
        int kb, nt;
        if (K == 128) { kb = (cid >> 6) & 3; nt = cid >> 8; }
        else          { kb = (cid >> 6) & 7; nt = cid >> 9; }
        int row = nt * 16 + (lane & 15);
        int col = kb * 32 + (lane >> 4) * 8;
        const float* pp = Wsrc + (size_t)row * K + col;
        f16 o8[8];
#pragma unroll
        for (int j = 0; j < 8; ++j) o8[j] = (f16)pp[j];
        *(h8*)(dstw + (size_t)cid * 8) = *(const h8*)o8;
    }
}

// --- K2: fused h-cast + QKV (512 thr). blocks [0,nsb) = scanA;
// blocks [nsb, nsb+slabs): stage h slab -> LDS+hb, then Q/K/V from LDS.
__global__ __launch_bounds__(512) void k_qkvf(
    const float* __restrict__ h, f16* __restrict__ hb,
    const f16* __restrict__ Wqb, const f16* __restrict__ Wkb,
    const f16* __restrict__ Wvb,
    f16* __restrict__ Qb, unsigned char* __restrict__ KV8,
    const int* __restrict__ cursor, int* __restrict__ bsum, int N, int nsb)
{
    __shared__ f16 sA[ND128];
    __shared__ int ws8[8];
    const int tid = threadIdx.x;
    if (blockIdx.x < (unsigned)nsb) {
        int base = blockIdx.x * 2048 + tid * 4;
        int s = 0;
#pragma unroll
        for (int j = 0; j < 4; ++j) {
            int idx = base + j;
            if (idx < N) s += cursor[idx];
        }
#pragma unroll
        for (int off = 32; off; off >>= 1) s += __shfl_down(s, off, 64);
        if ((tid & 63) == 0) ws8[tid >> 6] = s;
        __syncthreads();
        if (tid == 0) {
            int r = 0;
#pragma unroll
            for (int k = 0; k < 8; ++k) r += ws8[k];
            bsum[blockIdx.x] = r;
        }
        return;
    }
    const int slab = blockIdx.x - nsb;
#pragma unroll
    for (int it = 0; it < 4; ++it) {
        int cid = it * 512 + tid;              // 0..2047
        int lane = cid & 63;
        int m = (cid >> 6) & 7;
        int kb = cid >> 9;
        int row = slab * 128 + m * 16 + (lane & 15);
        int col = kb * 32 + (lane >> 4) * 8;
        f16 o8[8];
        if (row < N) {
            const float* pp = h + (size_t)row * 128 + col;
            float4 f0 = *(const float4*)pp;
            float4 f1 = *(const float4*)(pp + 4);
            o8[0] = (f16)f0.x; o8[1] = (f16)f0.y; o8[2] = (f16)f0.z; o8[3] = (f16)f0.w;
            o8[4] = (f16)f1.x; o8[5] = (f16)f1.y; o8[6] = (f16)f1.z; o8[7] = (f16)f1.w;
        } else {
#pragma unroll
            for (int j = 0; j < 8; ++j) o8[j] = (f16)0.f;
        }
        h8 v = *(const h8*)o8;
        *(h8*)(hb + (size_t)slab * ND128 + (size_t)cid * 8) = v;
        *(h8*)(sA + (size_t)cid * 8) = v;
    }
    __syncthreads();

    const int w2 = tid >> 6, lane = tid & 63;   // w2 = global nt index 0..7
    const int rl = lane & 15, quad = lane >> 4;
#pragma unroll
    for (int oidx = 0; oidx < 3; ++oidx) {
        const f16* __restrict__ Wb = oidx == 0 ? Wqb : oidx == 1 ? Wkb : Wvb;
        h8 bfr[4];
#pragma unroll
        for (int kb = 0; kb < 4; ++kb)
            bfr[kb] = *(const h8*)(Wb + (size_t)((w2 * 4 + kb) * 64 + lane) * 8);

        f4 acc[8];
        f4 zero = {0.f, 0.f, 0.f, 0.f};
#pragma unroll
        for (int m = 0; m < 8; ++m) acc[m] = zero;
#pragma unroll
        for (int m = 0; m < 8; ++m) {
#pragma unroll
            for (int kb = 0; kb < 4; ++kb) {
                h8 a = *(const h8*)(sA + (size_t)((kb * 8 + m) * 64 + lane) * 8);
                acc[m] = __builtin_amdgcn_mfma_f32_16x16x32_f16(bfr[kb], a, acc[m], 0, 0, 0);
            }
        }
        if (oidx == 0) {
#pragma unroll
            for (int m = 0; m < 8; ++m) {
                int gr = slab * 128 + m * 16 + rl;
                if (gr < N) {
                    h4 o;
                    o[0] = (f16)acc[m][0]; o[1] = (f16)acc[m][1];
                    o[2] = (f16)acc[m][2]; o[3] = (f16)acc[m][3];
                    *(h4*)(Qb + (size_t)gr * 128 + w2 * 16 + quad * 4) = o;
                }
            }
        } else {
            const int koff = (oidx == 2) ? 2 : 0;  // K -> bytes 0-1, V -> 2-3
#pragma unroll
            for (int m = 0; m < 8; ++m) {
                int gr = slab * 128 + m * 16 + rl;
                if (gr < N) {
                    int c0 = w2 * 16 + quad * 4;
                    unsigned short p01 = fp8_pack2(acc[m][0], acc[m][1]);
                    unsigned short p23 = fp8_pack2(acc[m][2], acc[m][3]);
                    unsigned char* rowp = KV8 + (size_t)gr * 256 + (size_t)c0 * 2 + koff;
                    *(unsigned short*)(rowp) = p01;
                    *(unsigned short*)(rowp + 4) = p23;
                }
            }
        }
    }
}

// --- scan part C ----------------------------------------------------------
__global__ __launch_bounds__(256) void k_scanC(
    const int* __restrict__ cnt, const int* __restrict__ bsum,
    int* __restrict__ rowptr, int* __restrict__ cursor, int N, int nsb)
{
    const int t = threadIdx.x, b = blockIdx.x;
    __shared__ int sboff;
    if (t == 0) {
        int r = 0;
        for (int i2 = 0; i2 < b; ++i2) r += bsum[i2];
        sboff = r;
    }
    if (t == 64 && b == nsb - 1) {
        int r = 0;
        for (int i2 = 0; i2 < nsb; ++i2) r += bsum[i2];
        rowptr[N] = r;
    }
    int base = b * 2048 + t * 8;
    int loc[8];
    int s = 0;
#pragma unroll
    for (int j = 0; j < 8; ++j) {
        int idx = base + j;
        loc[j] = (idx < N) ? cnt[idx] : 0;
        s += loc[j];
    }
    __shared__ int part[256];
    part[t] = s;
    __syncthreads();
    for (int off = 1; off < 256; off <<= 1) {
        int v = (t >= off) ? part[t - off] : 0;
        __syncthreads();
        part[t] += v;
        __syncthreads();
    }
    int run = sboff + (t ? part[t - 1] : 0);
#pragma unroll
    for (int j = 0; j < 8; ++j) {
        int idx = base + j;
        if (idx < N) { rowptr[idx] = run; cursor[idx] = run; run += loc[j]; }
    }
}

// --- scatter edges into CSR ------------------------------------------------
__global__ __launch_bounds__(256) void k_scatter(
    const int* __restrict__ src, const int* __restrict__ dst,
    int* __restrict__ cursor, int* __restrict__ csr_src, int E)
{
    int e = blockIdx.x * 256 + threadIdx.x;
    if (e < E) {
        int pos = atomicAdd(&cursor[dst[e]], 1);
        csr_src[pos] = src[e];
    }
}

// --- attention: one wave per node, lane owns channels (2l, 2l+1). ----------
// ONE dword gather per edge; 2-stage cross-chunk software pipeline (16
// outstanding gathers).
__global__ __launch_bounds__(256) void k_attn(
    const f16* __restrict__ Qb, const unsigned char* __restrict__ KV8,
    const int* __restrict__ rowptr, const int* __restrict__ csr_src,
    f16* __restrict__ attnf, int N)
{
    const int node = blockIdx.x * 4 + (threadIdx.x >> 6);
    const int lane = threadIdx.x & 63;
    if (node >= N) return;
    const int beg = rowptr[node], end = rowptr[node + 1];

    float qx, qy;
    {
        h2 q2 = ((const h2*)(Qb + (size_t)node * 128))[lane];
        const float SCL = 0.25f * 1.44269504f;
        qx = (float)q2[0] * SCL;
        qy = (float)q2[1] * SCL;
    }
    const float CLP = 5.f * 1.44269504f;
    const unsigned loff = 4u * (unsigned)lane;

    float axA = 0.f, ayA = 0.f, axB = 0.f, ayB = 0.f, zA = 0.f, zB = 0.f;
    int i = beg;
    const int nfull = (end - beg) >> 3;      // full 8-edge chunks
    unsigned kv[8];
    if (nfull > 0) {
#pragma unroll
        for (int u = 0; u < 8; ++u) {
            int s0 = csr_src[i + u];
            kv[u] = *(const unsigned*)(KV8 + (size_t)s0 * 256 + loff);
        }
    }
    for (int c = 0; c < nfull; ++c) {
        unsigned nkv[8];
        if (c + 1 < nfull) {
            int ni = i + 8;
#pragma unroll
            for (int u = 0; u < 8; ++u) {
                int s0 = csr_src[ni + u];
                nkv[u] = *(const unsigned*)(KV8 + (size_t)s0 * 256 + loff);
            }
        } else {
#pragma unroll
            for (int u = 0; u < 8; ++u) nkv[u] = 0u;
        }
        float p[8];
#pragma unroll
        for (int u = 0; u < 8; ++u) {
            ff2 kf = dec_lo(kv[u]);
            p[u] = fmaf(qx, kf.x, qy * kf.y);
        }
#pragma unroll
        for (int u = 0; u < 8; ++u) p[u] = wsum8(p[u]);
        float sc[8];
#pragma unroll
        for (int u = 0; u < 8; ++u)
            sc[u] = fast_exp2(fminf(fmaxf(p[u], -CLP), CLP));
#pragma unroll
        for (int u = 0; u < 8; ++u) {
            ff2 vf = dec_hi(kv[u]);
            if (u & 1) {
                axB = fmaf(vf.x, sc[u], axB); ayB = fmaf(vf.y, sc[u], ayB); zB += sc[u];
            } else {
                axA = fmaf(vf.x, sc[u], axA); ayA = fmaf(vf.y, sc[u], ayA); zA += sc[u];
            }
        }
#pragma unroll
        for (int u = 0; u < 8; ++u) kv[u] = nkv[u];
        i += 8;
    }
    if (i + 3 < end) {
        int s[4];
#pragma unroll
        for (int u = 0; u < 4; ++u) s[u] = csr_src[i + u];
        unsigned kt[4];
#pragma unroll
        for (int u = 0; u < 4; ++u)
            kt[u] = *(const unsigned*)(KV8 + (size_t)s[u] * 256 + loff);
#pragma unroll
        for (int u = 0; u < 4; ++u) {
            ff2 kf = dec_lo(kt[u]);
            float p = wsum8(fmaf(qx, kf.x, qy * kf.y));
            float scu = fast_exp2(fminf(fmaxf(p, -CLP), CLP));
            ff2 vf = dec_hi(kt[u]);
            if (u & 1) {
                axB = fmaf(vf.x, scu, axB); ayB = fmaf(vf.y, scu, ayB); zB += scu;
            } else {
                axA = fmaf(vf.x, scu, axA); ayA = fmaf(vf.y, scu, ayA); zA += scu;
            }
        }
        i += 4;
    }
    for (; i < end; ++i) {
        int s0 = csr_src[i];
        unsigned kvs = *(const unsigned*)(KV8 + (size_t)s0 * 256 + loff);
        ff2 kf = dec_lo(kvs);
        float p0 = wsum8(fmaf(qx, kf.x, qy * kf.y));
        float sc0 = fast_exp2(fminf(fmaxf(p0, -CLP), CLP));
        ff2 vf = dec_hi(kvs);
        axA = fmaf(vf.x, sc0, axA); ayA = fmaf(vf.y, sc0, ayA);
        zA += sc0;
    }
    float inv = 1.f / (zA + zB);
    h2 o2;
    o2[0] = (f16)((axA + axB) * inv);
    o2[1] = (f16)((ayA + ayB) * inv);
    int slab = node >> 7, m = (node >> 4) & 7, lr = node & 15;
    int kb = lane >> 4, quad2 = (lane & 15) >> 2, j = (lane & 3) * 2;
    *(h2*)(attnf + (size_t)slab * ND128 +
           (size_t)(((kb * 8 + m) * 64 + lr + 16 * quad2) * 8 + j)) = o2;
}

// --- O-proj (FAT): t1 = attn @ WO^T + h + bO -> f16 frag t1b; BN1 sums. ----
__global__ __launch_bounds__(256) void k_oproj(
    const f16* __restrict__ attnf, const f16* __restrict__ Wob,
    const f16* __restrict__ hbf, const float* __restrict__ bO,
    f16* __restrict__ t1b, float* __restrict__ bn, int N)
{
    __shared__ float csum[128], csq[128];
    const int tid = threadIdx.x, slab = blockIdx.x;
    const int w = tid >> 6, lane = tid & 63;
    if (tid < 128) { csum[tid] = 0.f; csq[tid] = 0.f; }
    __syncthreads();
    const f16* A = attnf + (size_t)slab * ND128;
    const f16* HB = hbf + (size_t)slab * ND128;

    h8 bfr[2][4];
#pragma unroll
    for (int nt = 0; nt < 2; ++nt)
#pragma unroll
        for (int kb = 0; kb < 4; ++kb)
            bfr[nt][kb] = *(const h8*)(Wob + (size_t)(((2 * w + nt) * 4 + kb) * 64 + lane) * 8);

    f4 acc[8][2];
    f4 zero = {0.f, 0.f, 0.f, 0.f};
#pragma unroll
    for (int m = 0; m < 8; ++m) { acc[m][0] = zero; acc[m][1] = zero; }
#pragma unroll
    for (int m = 0; m < 8; ++m) {
#pragma unroll
        for (int kb = 0; kb < 4; ++kb) {
            h8 a = *(const h8*)(A + (size_t)((kb * 8 + m) * 64 + lane) * 8);
            acc[m][0] = __builtin_amdgcn_mfma_f32_16x16x32_f16(bfr[0][kb], a, acc[m][0], 0, 0, 0);
            acc[m][1] = __builtin_amdgcn_mfma_f32_16x16x32_f16(bfr[1][kb], a, acc[m][1], 0, 0, 0);
        }
    }

    const int rl = lane & 15, quad = lane >> 4;
    float4 bo[2];
#pragma unroll
    for (int nt = 0; nt < 2; ++nt)
        bo[nt] = *(const float4*)(bO + w * 32 + nt * 16 + quad * 4);
    float pcs[2][4], pcq[2][4];
#pragma unroll
    for (int nt = 0; nt < 2; ++nt)
#pragma unroll
        for (int r = 0; r < 4; ++r) { pcs[nt][r] = 0.f; pcq[nt][r] = 0.f; }

#pragma unroll
    for (int m = 0; m < 8; ++m) {
        int gr = slab * 128 + m * 16 + rl;
        if (gr < N) {
#pragma unroll
            for (int nt = 0; nt < 2; ++nt) {
                size_t fidx = (size_t)(((w * 8 + m) * 64 + (nt * 2 + (quad >> 1)) * 16 + rl) * 8 +
                                       (quad & 1) * 4);
                h4 hv4 = *(const h4*)(HB + fidx);
                float v0 = acc[m][nt][0] + (float)hv4[0] + bo[nt].x;
                float v1 = acc[m][nt][1] + (float)hv4[1] + bo[nt].y;
                float v2 = acc[m][nt][2] + (float)hv4[2] + bo[nt].z;
                float v3 = acc[m][nt][3] + (float)hv4[3] + bo[nt].w;
                h4 o; o[0] = (f16)v0; o[1] = (f16)v1; o[2] = (f16)v2; o[3] = (f16)v3;
                *(h4*)(t1b + (size_t)slab * ND128 + fidx) = o;
                pcs[nt][0] += v0; pcq[nt][0] += v0 * v0;
                pcs[nt][1] += v1; pcq[nt][1] += v1 * v1;
                pcs[nt][2] += v2; pcq[nt][2] += v2 * v2;
                pcs[nt][3] += v3; pcq[nt][3] += v3 * v3;
            }
        }
    }
#pragma unroll
    for (int nt = 0; nt < 2; ++nt)
#pragma unroll
        for (int r = 0; r < 4; ++r) {
            float s = pcs[nt][r], q = pcq[nt][r];
            s += __shfl_xor(s, 8, 16); q += __shfl_xor(q, 8, 16);
            s += __shfl_xor(s, 4, 16); q += __shfl_xor(q, 4, 16);
            s += __shfl_xor(s, 2, 16); q += __shfl_xor(q, 2, 16);
            s += __shfl_xor(s, 1, 16); q += __shfl_xor(q, 1, 16);
            if (rl == 0) {
                int cl = w * 32 + nt * 16 + quad * 4 + r;
                atomicAdd(&csum[cl], s);
                atomicAdd(&csq[cl], q);
            }
        }
    __syncthreads();
    if (tid < 128) {
        atomicAdd(bn + tid, csum[tid]);
        atomicAdd(bn + 128 + tid, csq[tid]);
    }
}

// --- fold BN1 into W1/bias. 256 blocks (one per W1 row). -------------------
__global__ __launch_bounds__(128) void k_fold1(
    const float* __restrict__ bn, const float* __restrict__ g1,
    const float* __restrict__ bb1, const float* __restrict__ W1,
    const float* __restrict__ b1, f16* __restrict__ W1b,
    float* __restrict__ badj, float* __restrict__ sfold,
    float* __restrict__ bfold, int N)
{
    const int o = blockIdx.x, i = threadIdx.x;
    float invN = 1.f / (float)N;
    float mu = bn[i] * invN;
    float var = bn[128 + i] * invN - mu * mu;
    float s = g1[i] * rsqrtf(var + 1e-5f);
    float bb = bb1[i] - mu * s;
    if (o == 0) { sfold[i] = s; bfold[i] = bb; }
    float wv = W1[(size_t)o * 128 + i];
    __shared__ float red[128];
    red[i] = wv * bb;
    const int nt = o >> 4, lanelow = o & 15;
    const int kb = i >> 5, quad = (i >> 3) & 3, j = i & 7;
    W1b[(size_t)(((nt * 4 + kb) * 64 + lanelow + 16 * quad) * 8 + j)] = (f16)(wv * s);
    __syncthreads();
#pragma unroll
    for (int off = 64; off; off >>= 1) {
        if (i < off) red[i] += red[i + off];
        __syncthreads();
    }
    if (i == 0) badj[o] = b1[o] + red[0];
}

// --- FFN1 (FAT): u = relu(t1b @ W1s^T + badj). grid (slabs, 2). ------------
__global__ __launch_bounds__(256) void k_ffn1(
    const f16* __restrict__ t1b, const f16* __restrict__ W1b,
    const float* __restrict__ badj, f16* __restrict__ ub, int N)
{
    const int slab = blockIdx.x, ch = blockIdx.y;
    const int w = threadIdx.x >> 6, lane = threadIdx.x & 63;
    const f16* A = t1b + (size_t)slab * ND128;

    h8 bfr[2][4];
#pragma unroll
    for (int nt = 0; nt < 2; ++nt)
#pragma unroll
        for (int kb = 0; kb < 4; ++kb) {
            int ntg = ch * 8 + 2 * w + nt;
            bfr[nt][kb] = *(const h8*)(W1b + (size_t)((ntg * 4 + kb) * 64 + lane) * 8);
        }

    f4 acc[8][2];
    f4 zero = {0.f, 0.f, 0.f, 0.f};
#pragma unroll
    for (int m = 0; m < 8; ++m) { acc[m][0] = zero; acc[m][1] = zero; }
#pragma unroll
    for (int m = 0; m < 8; ++m) {
#pragma unroll
        for (int kb = 0; kb < 4; ++kb) {
            h8 a = *(const h8*)(A + (size_t)((kb * 8 + m) * 64 + lane) * 8);
            acc[m][0] = __builtin_amdgcn_mfma_f32_16x16x32_f16(bfr[0][kb], a, acc[m][0], 0, 0, 0);
            acc[m][1] = __builtin_amdgcn_mfma_f32_16x16x32_f16(bfr[1][kb], a, acc[m][1], 0, 0, 0);
        }
    }

    const int rl = lane & 15, quad = lane >> 4;
    const int kbu = ch * 4 + w;
    float4 ba[2];
#pragma unroll
    for (int nt = 0; nt < 2; ++nt)
        ba[nt] = *(const float4*)(badj + ch * 128 + w * 32 + nt * 16 + quad * 4);
#pragma unroll
    for (int m = 0; m < 8; ++m) {
        int gr = slab * 128 + m * 16 + rl;
        if (gr < N) {
#pragma unroll
            for (int nt = 0; nt < 2; ++nt) {
                h4 o;
                o[0] = (f16)fmaxf(acc[m][nt][0] + ba[nt].x, 0.f);
                o[1] = (f16)fmaxf(acc[m][nt][1] + ba[nt].y, 0.f);
                o[2] = (f16)fmaxf(acc[m][nt][2] + ba[nt].z, 0.f);
                o[3] = (f16)fmaxf(acc[m][nt][3] + ba[nt].w, 0.f);
                *(h4*)(ub + (size_t)slab * 32768 +
                       (size_t)(((kbu * 8 + m) * 64 + (nt * 2 + (quad >> 1)) * 16 + rl) * 8 +
                                (quad & 1) * 4)) = o;
            }
        }
    }
}

// --- FFN2 (FAT): t2 = (s1*t1 + b1v + b2) + u @ W2^T -> f16 frag t2f; -------
// BN2 stats computed FROM THE ROUNDED f16 values (stats/normalize consistent).
__global__ __launch_bounds__(256) void k_ffn2(
    const f16* __restrict__ ub, const f16* __restrict__ W2b,
    const f16* __restrict__ t1b,
    const float* __restrict__ sfold, const float* __restrict__ bfold,
    const float* __restrict__ b2, f16* __restrict__ t2f,
    float* __restrict__ bn, int N)
{
    __shared__ float csum[128], csq[128], sS[128], sB[128];
    const int tid = threadIdx.x, slab = blockIdx.x;
    const int w = tid >> 6, lane = tid & 63;
    if (tid < 128) {
        csum[tid] = 0.f; csq[tid] = 0.f;
        sS[tid] = sfold[tid]; sB[tid] = bfold[tid] + b2[tid];
    }
    __syncthreads();
    const f16* A = ub + (size_t)slab * 32768;
    const f16* T1 = t1b + (size_t)slab * ND128;

    h8 bfr[2][8];
#pragma unroll
    for (int nt = 0; nt < 2; ++nt)
#pragma unroll
        for (int kb = 0; kb < 8; ++kb)
            bfr[nt][kb] = *(const h8*)(W2b + (size_t)(((2 * w + nt) * 8 + kb) * 64 + lane) * 8);

    f4 acc[8][2];
    f4 zero = {0.f, 0.f, 0.f, 0.f};
#pragma unroll
    for (int m = 0; m < 8; ++m) { acc[m][0] = zero; acc[m][1] = zero; }
#pragma unroll
    for (int m = 0; m < 8; ++m) {
#pragma unroll
        for (int kb = 0; kb < 8; ++kb) {
            h8 a = *(const h8*)(A + (size_t)((kb * 8 + m) * 64 + lane) * 8);
            acc[m][0] = __builtin_amdgcn_mfma_f32_16x16x32_f16(bfr[0][kb], a, acc[m][0], 0, 0, 0);
            acc[m][1] = __builtin_amdgcn_mfma_f32_16x16x32_f16(bfr[1][kb], a, acc[m][1], 0, 0, 0);
        }
    }

    const int rl = lane & 15, quad = lane >> 4;
    float pcs[2][4], pcq[2][4];
#pragma unroll
    for (int nt = 0; nt < 2; ++nt)
#pragma unroll
        for (int r = 0; r < 4; ++r) { pcs[nt][r] = 0.f; pcq[nt][r] = 0.f; }

#pragma unroll
    for (int m = 0; m < 8; ++m) {
        int gr = slab * 128 + m * 16 + rl;
        if (gr < N) {
#pragma unroll
            for (int nt = 0; nt < 2; ++nt) {
                int col0 = w * 32 + nt * 16 + quad * 4;
                size_t fidx = (size_t)(((w * 8 + m) * 64 + (nt * 2 + (quad >> 1)) * 16 + rl) * 8 +
                                       (quad & 1) * 4);
                h4 t1v = *(const h4*)(T1 + fidx);
                float4 ss = *(const float4*)&sS[col0];
                float4 sb = *(const float4*)&sB[col0];
                h4 o2;
                o2[0] = (f16)(acc[m][nt][0] + fmaf(ss.x, (float)t1v[0], sb.x));
                o2[1] = (f16)(acc[m][nt][1] + fmaf(ss.y, (float)t1v[1], sb.y));
                o2[2] = (f16)(acc[m][nt][2] + fmaf(ss.z, (float)t1v[2], sb.z));
                o2[3] = (f16)(acc[m][nt][3] + fmaf(ss.w, (float)t1v[3], sb.w));
                *(h4*)(t2f + (size_t)slab * ND128 + fidx) = o2;
                float r0 = (float)o2[0], r1 = (float)o2[1];
                float r2 = (float)o2[2], r3 = (float)o2[3];
                pcs[nt][0] += r0; pcq[nt][0] += r0 * r0;
                pcs[nt][1] += r1; pcq[nt][1] += r1 * r1;
                pcs[nt][2] += r2; pcq[nt][2] += r2 * r2;
                pcs[nt][3] += r3; pcq[nt][3] += r3 * r3;
            }
        }
    }
#pragma unroll
    for (int nt = 0; nt < 2; ++nt)
#pragma unroll
        for (int r = 0; r < 4; ++r) {
            float s = pcs[nt][r], q = pcq[nt][r];
            s += __shfl_xor(s, 8, 16); q += __shfl_xor(q, 8, 16);
            s += __shfl_xor(s, 4, 16); q += __shfl_xor(q, 4, 16);
            s += __shfl_xor(s, 2, 16); q += __shfl_xor(q, 2, 16);
            s += __shfl_xor(s, 1, 16); q += __shfl_xor(q, 1, 16);
            if (rl == 0) {
                int cl = w * 32 + nt * 16 + quad * 4 + r;
                atomicAdd(&csum[cl], s);
                atomicAdd(&csq[cl], q);
            }
        }
    __syncthreads();
    if (tid < 128) {
        atomicAdd(bn + 256 + tid, csum[tid]);
        atomicAdd(bn + 384 + tid, csq[tid]);
    }
}

// --- BN2: read f16 t2 frags, normalize, write fp32 rows (coalesced). -------
__global__ __launch_bounds__(256) void k_bn2(
    const f16* __restrict__ t2f, float* __restrict__ out,
    const float* __restrict__ bn,
    const float* __restrict__ g2, const float* __restrict__ bb2, int N)
{
    __shared__ float sS[128], sB[128];
    const int tid = threadIdx.x;
    if (tid < 128) {
        float invN = 1.f / (float)N;
        float mu = bn[256 + tid] * invN;
        float var = bn[384 + tid] * invN - mu * mu;
        float scl = g2[tid] * rsqrtf(var + 1e-5f);
        sS[tid] = scl;
        sB[tid] = bb2[tid] - mu * scl;
    }
    __syncthreads();
    size_t idx = (size_t)blockIdx.x * 256 + tid;   // h4-group index
    size_t total = (size_t)N * 32;
    if (idx < total) {
        int gr = (int)(idx >> 5);
        int c0 = ((int)idx & 31) * 4;
        int slab = gr >> 7, m = (gr >> 4) & 7, rl = gr & 15;
        int w = c0 >> 5, nt = (c0 >> 4) & 1, q = (c0 >> 2) & 3;
        size_t fidx = (size_t)(((w * 8 + m) * 64 + (nt * 2 + (q >> 1)) * 16 + rl) * 8 +
                               (q & 1) * 4);
        h4 v = *(const h4*)(t2f + (size_t)slab * ND128 + fidx);
        float4 o;
        o.x = fmaf((float)v[0], sS[c0 + 0], sB[c0 + 0]);
        o.y = fmaf((float)v[1], sS[c0 + 1], sB[c0 + 1]);
        o.z = fmaf((float)v[2], sS[c0 + 2], sB[c0 + 2]);
        o.w = fmaf((float)v[3], sS[c0 + 3], sB[c0 + 3]);
        *(float4*)(out + (size_t)gr * 128 + c0) = o;
    }
}

extern "C" void kernel_launch(void* const* d_in, const int* in_sizes, int n_in,
                              void* d_out, int out_size, void* d_ws, size_t ws_size,
                              hipStream_t stream)
{
    const float* h   = (const float*)d_in[0];
    const int*   src = (const int*)d_in[1];
    const int*   dst = (const int*)d_in[2];
    const float* WQ  = (const float*)d_in[3];
    const float* WK  = (const float*)d_in[4];
    const float* WV  = (const float*)d_in[5];
    const float* WO  = (const float*)d_in[6];
    const float* bO  = (const float*)d_in[7];
    const float* W1  = (const float*)d_in[8];
    const float* b1  = (const float*)d_in[9];
    const float* W2  = (const float*)d_in[10];
    const float* b2  = (const float*)d_in[11];
    const float* g1  = (const float*)d_in[12];
    const float* bb1 = (const float*)d_in[13];
    const float* g2  = (const float*)d_in[14];
    const float* bb2 = (const float*)d_in[15];
    float* out = (float*)d_out;

    int N = in_sizes[0] / 128;
    int E = in_sizes[1];
    int slabs = (N + 127) / 128;
    int nsb = (N + 2047) / 2048;               // scan blocks (~25)
    int nhb = (E + 255) / 256;                 // edge blocks (~2500)
    const size_t B1 = (size_t)slabs * 32768;   // bytes of one f16 N_pad x 128 buffer

    char* Wp = (char*)d_ws;
    f16* hb  = (f16*)Wp;                       // h f16 frags, lives through oproj
    f16* Qb  = (f16*)(Wp + B1);                // B1
    unsigned char* KV8 = (unsigned char*)(Wp + 2 * B1);  // B1 (fp8 K|V interleaved words)
    f16* attnf = (f16*)(Wp + 3 * B1);          // B1; becomes t2f after ffn2
    f16* t1b = (f16*)(Wp + 4 * B1);            // B1
    f16* ub  = (f16*)(Wp + B1);                // 2*B1, overlays Qb+KV8 after attn
    f16* t2f = attnf;                          // attnf dead after oproj
    const size_t base = 5 * B1;
    f16* Wqb = (f16*)(Wp + base);
    f16* Wkb = (f16*)(Wp + base + 32768);
    f16* Wvb = (f16*)(Wp + base + 65536);
    f16* Wob = (f16*)(Wp + base + 98304);
    f16* W1b = (f16*)(Wp + base + 131072);
    f16* W2b = (f16*)(Wp + base + 196608);
    float* badj  = (float*)(Wp + base + 262144);
    float* sfold = (float*)(Wp + base + 263168);
    float* bfold = (float*)(Wp + base + 263680);
    float* bn    = (float*)(Wp + base + 264192);     // 512 floats (memset)
    int* bsum    = (int*)(Wp + base + 266240);       // 64 ints (memset)
    int* cursor  = (int*)(Wp + base + 266496);       // N ints (memset)
    int* rowptr  = (int*)(Wp + base + 266496 + (size_t)N * 4);
    int* csr     = (int*)(Wp + base + 266496 + (size_t)N * 8 + 8);

    // zero bn(2048) + bsum(256) + cursor(N*4) in one memset
    hipMemsetAsync(Wp + base + 264192, 0, 2304 + (size_t)N * 4, stream);
    k_prep_hist<<<nhb + 6, 256, 0, stream>>>(
        WQ, WK, WV, WO, W2, Wqb, Wkb, Wvb, Wob, W2b, cursor, dst, N, E, nhb);
    k_qkvf<<<nsb + slabs, 512, 0, stream>>>(
        h, hb, Wqb, Wkb, Wvb, Qb, KV8, cursor, bsum, N, nsb);
    k_scanC<<<nsb, 256, 0, stream>>>(cursor, bsum, rowptr, cursor, N, nsb);
    k_scatter<<<nhb, 256, 0, stream>>>(src, dst, cursor, csr, E);
    k_attn<<<(N + 3) / 4, 256, 0, stream>>>(Qb, KV8, rowptr, csr, attnf, N);
    k_oproj<<<slabs, 256, 0, stream>>>(attnf, Wob, hb, bO, t1b, bn, N);
    k_fold1<<<256, 128, 0, stream>>>(bn, g1, bb1, W1, b1, W1b, badj, sfold, bfold, N);
    k_ffn1<<<dim3(slabs, 2), 256, 0, stream>>>(t1b, W1b, badj, ub, N);
    k_ffn2<<<slabs, 256, 0, stream>>>(ub, W2b, t1b, sfold, bfold, b2, t2f, bn, N);
    k_bn2<<<(int)(((size_t)N * 32 + 255) / 256), 256, 0, stream>>>(t2f, out, bn, g2, bb2, N);
}

// Round 13
// 288.552 us; speedup vs baseline: 1.0850x; 1.0392x over previous
//
#include <hip/hip_runtime.h>
#include <math.h>

// ---------------------------------------------------------------------------
// GraphTransformerLayer N=50000, E=640000, D=128, H=8, DH=16  (gfx950)
// Round 24: R21/R23 base. attn pipeline reverted (neutral, R23). oproj/ffn2
// restructured to 512-thread blocks (8 waves, wave-per-ntg, full 8-m A-ILP
// per wave -> 2x waves/CU vs 4-wave fat blocks; the k_qkvf-proven shape).
// ffn1 also 512-thr (same total waves, fewer blocks). 512-thr stage-B
// indexing was correctness-verified by R22.
//
// Fragment order for an MxK slab (M=128, K=KB*32):
//   elem index = ((kb*8 + mtile)*64 + lane)*8 + j
//   row = mtile*16 + (lane&15),  col = kb*32 + (lane>>4)*8 + j
// Swapped-operand MFMA: mfma(Wfrag, hfrag) -> C^T: row = m*16+(lane&15),
// cols = ntg*16+quad*4+{0..3} contiguous.
// ---------------------------------------------------------------------------

#define ND128 16384
typedef _Float16 f16;
typedef __attribute__((ext_vector_type(8))) _Float16 h8;
typedef __attribute__((ext_vector_type(4))) _Float16 h4;
typedef __attribute__((ext_vector_type(2))) _Float16 h2;
typedef __attribute__((ext_vector_type(4))) float f4;
typedef __attribute__((ext_vector_type(2))) float ff2;

__device__ __forceinline__ float fast_exp2(float x) {
#if __has_builtin(__builtin_amdgcn_exp2f)
    return __builtin_amdgcn_exp2f(x);
#else
    return exp2f(x);
#endif
}

template <int CTRL>
__device__ __forceinline__ float dppadd(float x) {
    int t = __builtin_amdgcn_update_dpp(0, __float_as_int(x), CTRL, 0xF, 0xF, false);
    return x + __int_as_float(t);
}
__device__ __forceinline__ float wsum8(float p) {
    p = dppadd<0xB1>(p);    // quad_perm [1,0,3,2]
    p = dppadd<0x4E>(p);    // quad_perm [2,3,0,1]
    p = dppadd<0x141>(p);   // row_half_mirror
    return p;
}

__device__ __forceinline__ ff2 fp8x2_dec_sw(unsigned v) {
    ff2 r;
    unsigned b0 = v & 0xffu, b1 = (v >> 8) & 0xffu;
    {
        unsigned e = (b0 >> 3) & 15u, m = b0 & 7u;
        float x = e ? __uint_as_float(((e + 120u) << 23) | (m << 20)) : (float)m * 0.001953125f;
        r.x = (b0 & 0x80u) ? -x : x;
    }
    {
        unsigned e = (b1 >> 3) & 15u, m = b1 & 7u;
        float x = e ? __uint_as_float(((e + 120u) << 23) | (m << 20)) : (float)m * 0.001953125f;
        r.y = (b1 & 0x80u) ? -x : x;
    }
    return r;
}

__device__ __forceinline__ ff2 dec_lo(unsigned v) {
#if __has_builtin(__builtin_amdgcn_cvt_pk_f32_fp8)
    return __builtin_amdgcn_cvt_pk_f32_fp8((int)v, false);
#else
    return fp8x2_dec_sw(v & 0xffffu);
#endif
}
__device__ __forceinline__ ff2 dec_hi(unsigned v) {
#if __has_builtin(__builtin_amdgcn_cvt_pk_f32_fp8)
    return __builtin_amdgcn_cvt_pk_f32_fp8((int)v, true);
#else
    return fp8x2_dec_sw((v >> 16) & 0xffffu);
#endif
}

#if !__has_builtin(__builtin_amdgcn_cvt_pk_fp8_f32)
__device__ __forceinline__ unsigned char fp8_1(float f) {
    float a = fabsf(f);
    unsigned sg = (__float_as_uint(f) >> 31) << 7;
    if (a >= 448.f) return (unsigned char)(sg | 0x7E);
    if (a < 0.0009765625f) return (unsigned char)sg;
    int E; float m = frexpf(a, &E);
    if (E - 1 < -6) {
        int q = (int)rintf(a * 512.f);
        if (q > 7) return (unsigned char)(sg | 0x08);
        return (unsigned char)(sg | q);
    }
    int q = (int)rintf(m * 16.f);
    if (q == 16) { q = 8; E += 1; }
    int Ef = E - 1 + 7;
    if (Ef > 15) return (unsigned char)(sg | 0x7E);
    return (unsigned char)(sg | (Ef << 3) | (q - 8));
}
#endif

__device__ __forceinline__ unsigned short fp8_pack2(float a0, float a1) {
#if __has_builtin(__builtin_amdgcn_cvt_pk_fp8_f32)
    int pk = __builtin_amdgcn_cvt_pk_fp8_f32(a0, a1, 0, false);
    return (unsigned short)(pk & 0xffff);
#else
    return (unsigned short)((unsigned)fp8_1(a0) | ((unsigned)fp8_1(a1) << 8));
#endif
}

// --- K1: hist (blocks [0,nhb)) UNION weight casts (blocks [nhb, nhb+6)). ---
__global__ __launch_bounds__(256) void k_prep_hist(
    const float* __restrict__ WQ, const float* __restrict__ WK,
    const float* __restrict__ WV, const float* __restrict__ WO,
    const float* __restrict__ W2,
    f16* __restrict__ Wqb, f16* __restrict__ Wkb,
    f16* __restrict__ Wvb, f16* __restrict__ Wob, f16* __restrict__ W2b,
    int* __restrict__ cursor, const int* __restrict__ dst,
    int N, int E, int nhb)
{
    const int tid = threadIdx.x;
    if (blockIdx.x < (unsigned)nhb) {
        int e = blockIdx.x * 256 + tid;
        if (e < E) atomicAdd(&cursor[dst[e]], 1);
        return;
    }
    const int ws = blockIdx.x - nhb;           // 0..5
    const float* Wsrc; f16* dstw; int K, base;
    if (ws < 4) {
        Wsrc = ws == 0 ? WQ : ws == 1 ? WK : ws == 2 ? WV : WO;
        dstw = ws == 0 ? Wqb : ws == 1 ? Wkb : ws == 2 ? Wvb : Wob;
        K = 128; base = 0;
    } else {
        Wsrc = W2; dstw = W2b; K = 256; base = (ws - 4) * 2048;
    }
#pragma unroll
    for (int it = 0; it < 8; ++it) {
        int cid = base + it * 256 + tid;
        int lane = cid & 63;
        int kb, nt;
        if (K == 128) { kb = (cid >> 6) & 3; nt = cid >> 8; }
        else          { kb = (cid >> 6) & 7; nt = cid >> 9; }
        int row = nt * 16 + (lane & 15);
        int col = kb * 32 + (lane >> 4) * 8;
        const float* pp = Wsrc + (size_t)row * K + col;
        f16 o8[8];
#pragma unroll
        for (int j = 0; j < 8; ++j) o8[j] = (f16)pp[j];
        *(h8*)(dstw + (size_t)cid * 8) = *(const h8*)o8;
    }
}

// --- K2: fused h-cast + QKV (512 thr). blocks [0,nsb) = scanA;
// blocks [nsb, nsb+slabs): stage h slab -> LDS+hb, then Q/K/V from LDS.
__global__ __launch_bounds__(512) void k_qkvf(
    const float* __restrict__ h, f16* __restrict__ hb,
    const f16* __restrict__ Wqb, const f16* __restrict__ Wkb,
    const f16* __restrict__ Wvb,
    f16* __restrict__ Qb, unsigned char* __restrict__ KV8,
    const int* __restrict__ cursor, int* __restrict__ bsum, int N, int nsb)
{
    __shared__ f16 sA[ND128];
    __shared__ int ws8[8];
    const int tid = threadIdx.x;
    if (blockIdx.x < (unsigned)nsb) {
        int base = blockIdx.x * 2048 + tid * 4;
        int s = 0;
#pragma unroll
        for (int j = 0; j < 4; ++j) {
            int idx = base + j;
            if (idx < N) s += cursor[idx];
        }
#pragma unroll
        for (int off = 32; off; off >>= 1) s += __shfl_down(s, off, 64);
        if ((tid & 63) == 0) ws8[tid >> 6] = s;
        __syncthreads();
        if (tid == 0) {
            int r = 0;
#pragma unroll
            for (int k = 0; k < 8; ++k) r += ws8[k];
            bsum[blockIdx.x] = r;
        }
        return;
    }
    const int slab = blockIdx.x - nsb;
#pragma unroll
    for (int it = 0; it < 4; ++it) {
        int cid = it * 512 + tid;              // 0..2047
        int lane = cid & 63;
        int m = (cid >> 6) & 7;
        int kb = cid >> 9;
        int row = slab * 128 + m * 16 + (lane & 15);
        int col = kb * 32 + (lane >> 4) * 8;
        f16 o8[8];
        if (row < N) {
            const float* pp = h + (size_t)row * 128 + col;
            float4 f0 = *(const float4*)pp;
            float4 f1 = *(const float4*)(pp + 4);
            o8[0] = (f16)f0.x; o8[1] = (f16)f0.y; o8[2] = (f16)f0.z; o8[3] = (f16)f0.w;
            o8[4] = (f16)f1.x; o8[5] = (f16)f1.y; o8[6] = (f16)f1.z; o8[7] = (f16)f1.w;
        } else {
#pragma unroll
            for (int j = 0; j < 8; ++j) o8[j] = (f16)0.f;
        }
        h8 v = *(const h8*)o8;
        *(h8*)(hb + (size_t)slab * ND128 + (size_t)cid * 8) = v;
        *(h8*)(sA + (size_t)cid * 8) = v;
    }
    __syncthreads();

    const int w2 = tid >> 6, lane = tid & 63;   // w2 = global nt index 0..7
    const int rl = lane & 15, quad = lane >> 4;
#pragma unroll
    for (int oidx = 0; oidx < 3; ++oidx) {
        const f16* __restrict__ Wb = oidx == 0 ? Wqb : oidx == 1 ? Wkb : Wvb;
        h8 bfr[4];
#pragma unroll
        for (int kb = 0; kb < 4; ++kb)
            bfr[kb] = *(const h8*)(Wb + (size_t)((w2 * 4 + kb) * 64 + lane) * 8);

        f4 acc[8];
        f4 zero = {0.f, 0.f, 0.f, 0.f};
#pragma unroll
        for (int m = 0; m < 8; ++m) acc[m] = zero;
#pragma unroll
        for (int m = 0; m < 8; ++m) {
#pragma unroll
            for (int kb = 0; kb < 4; ++kb) {
                h8 a = *(const h8*)(sA + (size_t)((kb * 8 + m) * 64 + lane) * 8);
                acc[m] = __builtin_amdgcn_mfma_f32_16x16x32_f16(bfr[kb], a, acc[m], 0, 0, 0);
            }
        }
        if (oidx == 0) {
#pragma unroll
            for (int m = 0; m < 8; ++m) {
                int gr = slab * 128 + m * 16 + rl;
                if (gr < N) {
                    h4 o;
                    o[0] = (f16)acc[m][0]; o[1] = (f16)acc[m][1];
                    o[2] = (f16)acc[m][2]; o[3] = (f16)acc[m][3];
                    *(h4*)(Qb + (size_t)gr * 128 + w2 * 16 + quad * 4) = o;
                }
            }
        } else {
            const int koff = (oidx == 2) ? 2 : 0;  // K -> bytes 0-1, V -> 2-3
#pragma unroll
            for (int m = 0; m < 8; ++m) {
                int gr = slab * 128 + m * 16 + rl;
                if (gr < N) {
                    int c0 = w2 * 16 + quad * 4;
                    unsigned short p01 = fp8_pack2(acc[m][0], acc[m][1]);
                    unsigned short p23 = fp8_pack2(acc[m][2], acc[m][3]);
                    unsigned char* rowp = KV8 + (size_t)gr * 256 + (size_t)c0 * 2 + koff;
                    *(unsigned short*)(rowp) = p01;
                    *(unsigned short*)(rowp + 4) = p23;
                }
            }
        }
    }
}

// --- scan part C ----------------------------------------------------------
__global__ __launch_bounds__(256) void k_scanC(
    const int* __restrict__ cnt, const int* __restrict__ bsum,
    int* __restrict__ rowptr, int* __restrict__ cursor, int N, int nsb)
{
    const int t = threadIdx.x, b = blockIdx.x;
    __shared__ int sboff;
    if (t == 0) {
        int r = 0;
        for (int i2 = 0; i2 < b; ++i2) r += bsum[i2];
        sboff = r;
    }
    if (t == 64 && b == nsb - 1) {
        int r = 0;
        for (int i2 = 0; i2 < nsb; ++i2) r += bsum[i2];
        rowptr[N] = r;
    }
    int base = b * 2048 + t * 8;
    int loc[8];
    int s = 0;
#pragma unroll
    for (int j = 0; j < 8; ++j) {
        int idx = base + j;
        loc[j] = (idx < N) ? cnt[idx] : 0;
        s += loc[j];
    }
    __shared__ int part[256];
    part[t] = s;
    __syncthreads();
    for (int off = 1; off < 256; off <<= 1) {
        int v = (t >= off) ? part[t - off] : 0;
        __syncthreads();
        part[t] += v;
        __syncthreads();
    }
    int run = sboff + (t ? part[t - 1] : 0);
#pragma unroll
    for (int j = 0; j < 8; ++j) {
        int idx = base + j;
        if (idx < N) { rowptr[idx] = run; cursor[idx] = run; run += loc[j]; }
    }
}

// --- scatter edges into CSR ------------------------------------------------
__global__ __launch_bounds__(256) void k_scatter(
    const int* __restrict__ src, const int* __restrict__ dst,
    int* __restrict__ cursor, int* __restrict__ csr_src, int E)
{
    int e = blockIdx.x * 256 + threadIdx.x;
    if (e < E) {
        int pos = atomicAdd(&cursor[dst[e]], 1);
        csr_src[pos] = src[e];
    }
}

// --- attention: one wave per node, lane owns channels (2l, 2l+1). ----------
// ONE dword gather per edge: dec_lo -> K pair, dec_hi -> V pair. (R21 form.)
__global__ __launch_bounds__(256) void k_attn(
    const f16* __restrict__ Qb, const unsigned char* __restrict__ KV8,
    const int* __restrict__ rowptr, const int* __restrict__ csr_src,
    f16* __restrict__ attnf, int N)
{
    const int node = blockIdx.x * 4 + (threadIdx.x >> 6);
    const int lane = threadIdx.x & 63;
    if (node >= N) return;
    const int beg = rowptr[node], end = rowptr[node + 1];

    float qx, qy;
    {
        h2 q2 = ((const h2*)(Qb + (size_t)node * 128))[lane];
        const float SCL = 0.25f * 1.44269504f;
        qx = (float)q2[0] * SCL;
        qy = (float)q2[1] * SCL;
    }
    const float CLP = 5.f * 1.44269504f;
    const unsigned loff = 4u * (unsigned)lane;

    float axA = 0.f, ayA = 0.f, axB = 0.f, ayB = 0.f, zA = 0.f, zB = 0.f;
    int i = beg;
    for (; i + 7 < end; i += 8) {
        int s[8];
#pragma unroll
        for (int u = 0; u < 8; ++u) s[u] = csr_src[i + u];
        unsigned kv[8];
#pragma unroll
        for (int u = 0; u < 8; ++u)
            kv[u] = *(const unsigned*)(KV8 + (size_t)s[u] * 256 + loff);
        float p[8];
#pragma unroll
        for (int u = 0; u < 8; ++u) {
            ff2 kf = dec_lo(kv[u]);
            p[u] = fmaf(qx, kf.x, qy * kf.y);
        }
#pragma unroll
        for (int u = 0; u < 8; ++u) p[u] = wsum8(p[u]);
        float sc[8];
#pragma unroll
        for (int u = 0; u < 8; ++u)
            sc[u] = fast_exp2(fminf(fmaxf(p[u], -CLP), CLP));
#pragma unroll
        for (int u = 0; u < 8; ++u) {
            ff2 vf = dec_hi(kv[u]);
            if (u & 1) {
                axB = fmaf(vf.x, sc[u], axB); ayB = fmaf(vf.y, sc[u], ayB); zB += sc[u];
            } else {
                axA = fmaf(vf.x, sc[u], axA); ayA = fmaf(vf.y, sc[u], ayA); zA += sc[u];
            }
        }
    }
    if (i + 3 < end) {
        int s[4];
#pragma unroll
        for (int u = 0; u < 4; ++u) s[u] = csr_src[i + u];
        unsigned kv[4];
#pragma unroll
        for (int u = 0; u < 4; ++u)
            kv[u] = *(const unsigned*)(KV8 + (size_t)s[u] * 256 + loff);
#pragma unroll
        for (int u = 0; u < 4; ++u) {
            ff2 kf = dec_lo(kv[u]);
            float p = wsum8(fmaf(qx, kf.x, qy * kf.y));
            float scu = fast_exp2(fminf(fmaxf(p, -CLP), CLP));
            ff2 vf = dec_hi(kv[u]);
            if (u & 1) {
                axB = fmaf(vf.x, scu, axB); ayB = fmaf(vf.y, scu, ayB); zB += scu;
            } else {
                axA = fmaf(vf.x, scu, axA); ayA = fmaf(vf.y, scu, ayA); zA += scu;
            }
        }
        i += 4;
    }
    for (; i < end; ++i) {
        int s0 = csr_src[i];
        unsigned kv = *(const unsigned*)(KV8 + (size_t)s0 * 256 + loff);
        ff2 kf = dec_lo(kv);
        float p0 = wsum8(fmaf(qx, kf.x, qy * kf.y));
        float sc0 = fast_exp2(fminf(fmaxf(p0, -CLP), CLP));
        ff2 vf = dec_hi(kv);
        axA = fmaf(vf.x, sc0, axA); ayA = fmaf(vf.y, sc0, ayA);
        zA += sc0;
    }
    float inv = 1.f / (zA + zB);
    h2 o2;
    o2[0] = (f16)((axA + axB) * inv);
    o2[1] = (f16)((ayA + ayB) * inv);
    int slab = node >> 7, m = (node >> 4) & 7, lr = node & 15;
    int kb = lane >> 4, quad2 = (lane & 15) >> 2, j = (lane & 3) * 2;
    *(h2*)(attnf + (size_t)slab * ND128 +
           (size_t)(((kb * 8 + m) * 64 + lr + 16 * quad2) * 8 + j)) = o2;
}

// --- O-proj (512 thr, wave-per-ntg): t1 = attn @ WO^T + h + bO; BN1 sums. --
__global__ __launch_bounds__(512) void k_oproj(
    const f16* __restrict__ attnf, const f16* __restrict__ Wob,
    const f16* __restrict__ hbf, const float* __restrict__ bO,
    f16* __restrict__ t1b, float* __restrict__ bn, int N)
{
    __shared__ float csum[128], csq[128];
    const int tid = threadIdx.x, slab = blockIdx.x;
    const int w2 = tid >> 6, lane = tid & 63;
    const int rl = lane & 15, quad = lane >> 4;
    if (tid < 128) { csum[tid] = 0.f; csq[tid] = 0.f; }
    __syncthreads();
    const f16* A = attnf + (size_t)slab * ND128;
    const f16* HB = hbf + (size_t)slab * ND128;

    h8 bfr[4];
#pragma unroll
    for (int kb = 0; kb < 4; ++kb)
        bfr[kb] = *(const h8*)(Wob + (size_t)((w2 * 4 + kb) * 64 + lane) * 8);

    f4 acc[8];
    f4 zero = {0.f, 0.f, 0.f, 0.f};
#pragma unroll
    for (int m = 0; m < 8; ++m) acc[m] = zero;
#pragma unroll
    for (int m = 0; m < 8; ++m) {
#pragma unroll
        for (int kb = 0; kb < 4; ++kb) {
            h8 a = *(const h8*)(A + (size_t)((kb * 8 + m) * 64 + lane) * 8);
            acc[m] = __builtin_amdgcn_mfma_f32_16x16x32_f16(bfr[kb], a, acc[m], 0, 0, 0);
        }
    }

    const int c0 = w2 * 16 + quad * 4;
    float4 bo = *(const float4*)(bO + c0);
    float pcs[4] = {0.f, 0.f, 0.f, 0.f};
    float pcq[4] = {0.f, 0.f, 0.f, 0.f};
#pragma unroll
    for (int m = 0; m < 8; ++m) {
        int gr = slab * 128 + m * 16 + rl;
        if (gr < N) {
            size_t fidx = (size_t)((((w2 >> 1) * 8 + m) * 64 +
                          ((w2 & 1) * 2 + (quad >> 1)) * 16 + rl) * 8 + (quad & 1) * 4);
            h4 hv4 = *(const h4*)(HB + fidx);
            float v0 = acc[m][0] + (float)hv4[0] + bo.x;
            float v1 = acc[m][1] + (float)hv4[1] + bo.y;
            float v2 = acc[m][2] + (float)hv4[2] + bo.z;
            float v3 = acc[m][3] + (float)hv4[3] + bo.w;
            h4 o; o[0] = (f16)v0; o[1] = (f16)v1; o[2] = (f16)v2; o[3] = (f16)v3;
            *(h4*)(t1b + (size_t)slab * ND128 + fidx) = o;
            pcs[0] += v0; pcq[0] += v0 * v0;
            pcs[1] += v1; pcq[1] += v1 * v1;
            pcs[2] += v2; pcq[2] += v2 * v2;
            pcs[3] += v3; pcq[3] += v3 * v3;
        }
    }
#pragma unroll
    for (int r = 0; r < 4; ++r) {
        float s = pcs[r], q = pcq[r];
        s += __shfl_xor(s, 8, 16); q += __shfl_xor(q, 8, 16);
        s += __shfl_xor(s, 4, 16); q += __shfl_xor(q, 4, 16);
        s += __shfl_xor(s, 2, 16); q += __shfl_xor(q, 2, 16);
        s += __shfl_xor(s, 1, 16); q += __shfl_xor(q, 1, 16);
        if (rl == 0) {
            atomicAdd(&csum[c0 + r], s);
            atomicAdd(&csq[c0 + r], q);
        }
    }
    __syncthreads();
    if (tid < 128) {
        atomicAdd(bn + tid, csum[tid]);
        atomicAdd(bn + 128 + tid, csq[tid]);
    }
}

// --- fold BN1 into W1/bias. 256 blocks (one per W1 row). -------------------
__global__ __launch_bounds__(128) void k_fold1(
    const float* __restrict__ bn, const float* __restrict__ g1,
    const float* __restrict__ bb1, const float* __restrict__ W1,
    const float* __restrict__ b1, f16* __restrict__ W1b,
    float* __restrict__ badj, float* __restrict__ sfold,
    float* __restrict__ bfold, int N)
{
    const int o = blockIdx.x, i = threadIdx.x;
    float invN = 1.f / (float)N;
    float mu = bn[i] * invN;
    float var = bn[128 + i] * invN - mu * mu;
    float s = g1[i] * rsqrtf(var + 1e-5f);
    float bb = bb1[i] - mu * s;
    if (o == 0) { sfold[i] = s; bfold[i] = bb; }
    float wv = W1[(size_t)o * 128 + i];
    __shared__ float red[128];
    red[i] = wv * bb;
    const int nt = o >> 4, lanelow = o & 15;
    const int kb = i >> 5, quad = (i >> 3) & 3, j = i & 7;
    W1b[(size_t)(((nt * 4 + kb) * 64 + lanelow + 16 * quad) * 8 + j)] = (f16)(wv * s);
    __syncthreads();
#pragma unroll
    for (int off = 64; off; off >>= 1) {
        if (i < off) red[i] += red[i + off];
        __syncthreads();
    }
    if (i == 0) badj[o] = b1[o] + red[0];
}

// --- FFN1 (512 thr): u = relu(t1b @ W1s^T + badj). grid = slabs. -----------
// wave w2: ch = w2>>2, wl = w2&3 (identical per-wave work to old (slabs,2)).
__global__ __launch_bounds__(512) void k_ffn1(
    const f16* __restrict__ t1b, const f16* __restrict__ W1b,
    const float* __restrict__ badj, f16* __restrict__ ub, int N)
{
    const int slab = blockIdx.x;
    const int w2 = threadIdx.x >> 6, lane = threadIdx.x & 63;
    const int ch = w2 >> 2, wl = w2 & 3;
    const f16* A = t1b + (size_t)slab * ND128;

    h8 bfr[2][4];
#pragma unroll
    for (int nt = 0; nt < 2; ++nt)
#pragma unroll
        for (int kb = 0; kb < 4; ++kb) {
            int ntg = ch * 8 + 2 * wl + nt;
            bfr[nt][kb] = *(const h8*)(W1b + (size_t)((ntg * 4 + kb) * 64 + lane) * 8);
        }

    f4 acc[8][2];
    f4 zero = {0.f, 0.f, 0.f, 0.f};
#pragma unroll
    for (int m = 0; m < 8; ++m) { acc[m][0] = zero; acc[m][1] = zero; }
#pragma unroll
    for (int m = 0; m < 8; ++m) {
#pragma unroll
        for (int kb = 0; kb < 4; ++kb) {
            h8 a = *(const h8*)(A + (size_t)((kb * 8 + m) * 64 + lane) * 8);
            acc[m][0] = __builtin_amdgcn_mfma_f32_16x16x32_f16(bfr[0][kb], a, acc[m][0], 0, 0, 0);
            acc[m][1] = __builtin_amdgcn_mfma_f32_16x16x32_f16(bfr[1][kb], a, acc[m][1], 0, 0, 0);
        }
    }

    const int rl = lane & 15, quad = lane >> 4;
    const int kbu = ch * 4 + wl;
    float4 ba[2];
#pragma unroll
    for (int nt = 0; nt < 2; ++nt)
        ba[nt] = *(const float4*)(badj + ch * 128 + wl * 32 + nt * 16 + quad * 4);
#pragma unroll
    for (int m = 0; m < 8; ++m) {
        int gr = slab * 128 + m * 16 + rl;
        if (gr < N) {
#pragma unroll
            for (int nt = 0; nt < 2; ++nt) {
                h4 o;
                o[0] = (f16)fmaxf(acc[m][nt][0] + ba[nt].x, 0.f);
                o[1] = (f16)fmaxf(acc[m][nt][1] + ba[nt].y, 0.f);
                o[2] = (f16)fmaxf(acc[m][nt][2] + ba[nt].z, 0.f);
                o[3] = (f16)fmaxf(acc[m][nt][3] + ba[nt].w, 0.f);
                *(h4*)(ub + (size_t)slab * 32768 +
                       (size_t)(((kbu * 8 + m) * 64 + (nt * 2 + (quad >> 1)) * 16 + rl) * 8 +
                                (quad & 1) * 4)) = o;
            }
        }
    }
}

// --- FFN2 (512 thr, wave-per-ntg): t2 = (s1*t1+b1v+b2) + u @ W2^T -> t2f; --
// BN2 stats from rounded f16 values (stats/normalize consistent).
__global__ __launch_bounds__(512) void k_ffn2(
    const f16* __restrict__ ub, const f16* __restrict__ W2b,
    const f16* __restrict__ t1b,
    const float* __restrict__ sfold, const float* __restrict__ bfold,
    const float* __restrict__ b2, f16* __restrict__ t2f,
    float* __restrict__ bn, int N)
{
    __shared__ float csum[128], csq[128];
    const int tid = threadIdx.x, slab = blockIdx.x;
    const int w2 = tid >> 6, lane = tid & 63;
    const int rl = lane & 15, quad = lane >> 4;
    if (tid < 128) { csum[tid] = 0.f; csq[tid] = 0.f; }
    __syncthreads();
    const f16* A = ub + (size_t)slab * 32768;
    const f16* T1 = t1b + (size_t)slab * ND128;

    h8 bfr2[8];
#pragma unroll
    for (int kb = 0; kb < 8; ++kb)
        bfr2[kb] = *(const h8*)(W2b + (size_t)((w2 * 8 + kb) * 64 + lane) * 8);

    f4 acc2[8];
    f4 zero = {0.f, 0.f, 0.f, 0.f};
#pragma unroll
    for (int m = 0; m < 8; ++m) acc2[m] = zero;
#pragma unroll
    for (int m = 0; m < 8; ++m) {
#pragma unroll
        for (int kb = 0; kb < 8; ++kb) {
            h8 a = *(const h8*)(A + (size_t)((kb * 8 + m) * 64 + lane) * 8);
            acc2[m] = __builtin_amdgcn_mfma_f32_16x16x32_f16(bfr2[kb], a, acc2[m], 0, 0, 0);
        }
    }

    const int c0 = w2 * 16 + quad * 4;
    float4 ss = *(const float4*)(sfold + c0);
    float4 sbA = *(const float4*)(bfold + c0);
    float4 sbB = *(const float4*)(b2 + c0);
    float4 sb;
    sb.x = sbA.x + sbB.x; sb.y = sbA.y + sbB.y;
    sb.z = sbA.z + sbB.z; sb.w = sbA.w + sbB.w;

    float pcs[4] = {0.f, 0.f, 0.f, 0.f};
    float pcq[4] = {0.f, 0.f, 0.f, 0.f};
#pragma unroll
    for (int m = 0; m < 8; ++m) {
        int gr = slab * 128 + m * 16 + rl;
        if (gr < N) {
            size_t fidx = (size_t)((((w2 >> 1) * 8 + m) * 64 +
                          ((w2 & 1) * 2 + (quad >> 1)) * 16 + rl) * 8 + (quad & 1) * 4);
            h4 t1v = *(const h4*)(T1 + fidx);
            h4 o2;
            o2[0] = (f16)(acc2[m][0] + fmaf(ss.x, (float)t1v[0], sb.x));
            o2[1] = (f16)(acc2[m][1] + fmaf(ss.y, (float)t1v[1], sb.y));
            o2[2] = (f16)(acc2[m][2] + fmaf(ss.z, (float)t1v[2], sb.z));
            o2[3] = (f16)(acc2[m][3] + fmaf(ss.w, (float)t1v[3], sb.w));
            *(h4*)(t2f + (size_t)slab * ND128 + fidx) = o2;
            float r0 = (float)o2[0], r1 = (float)o2[1];
            float r2 = (float)o2[2], r3 = (float)o2[3];
            pcs[0] += r0; pcq[0] += r0 * r0;
            pcs[1] += r1; pcq[1] += r1 * r1;
            pcs[2] += r2; pcq[2] += r2 * r2;
            pcs[3] += r3; pcq[3] += r3 * r3;
        }
    }
#pragma unroll
    for (int r = 0; r < 4; ++r) {
        float s = pcs[r], q = pcq[r];
        s += __shfl_xor(s, 8, 16); q += __shfl_xor(q, 8, 16);
        s += __shfl_xor(s, 4, 16); q += __shfl_xor(q, 4, 16);
        s += __shfl_xor(s, 2, 16); q += __shfl_xor(q, 2, 16);
        s += __shfl_xor(s, 1, 16); q += __shfl_xor(q, 1, 16);
        if (rl == 0) {
            atomicAdd(&csum[c0 + r], s);
            atomicAdd(&csq[c0 + r], q);
        }
    }
    __syncthreads();
    if (tid < 128) {
        atomicAdd(bn + 256 + tid, csum[tid]);
        atomicAdd(bn + 384 + tid, csq[tid]);
    }
}

// --- BN2: read f16 t2 frags, normalize, write fp32 rows (coalesced). -------
__global__ __launch_bounds__(256) void k_bn2(
    const f16* __restrict__ t2f, float* __restrict__ out,
    const float* __restrict__ bn,
    const float* __restrict__ g2, const float* __restrict__ bb2, int N)
{
    __shared__ float sS[128], sB[128];
    const int tid = threadIdx.x;
    if (tid < 128) {
        float invN = 1.f / (float)N;
        float mu = bn[256 + tid] * invN;
        float var = bn[384 + tid] * invN - mu * mu;
        float scl = g2[tid] * rsqrtf(var + 1e-5f);
        sS[tid] = scl;
        sB[tid] = bb2[tid] - mu * scl;
    }
    __syncthreads();
    size_t idx = (size_t)blockIdx.x * 256 + tid;   // h4-group index
    size_t total = (size_t)N * 32;
    if (idx < total) {
        int gr = (int)(idx >> 5);
        int c0 = ((int)idx & 31) * 4;
        int slab = gr >> 7, m = (gr >> 4) & 7, rl = gr & 15;
        int w = c0 >> 5, nt = (c0 >> 4) & 1, q = (c0 >> 2) & 3;
        size_t fidx = (size_t)(((w * 8 + m) * 64 + (nt * 2 + (q >> 1)) * 16 + rl) * 8 +
                               (q & 1) * 4);
        h4 v = *(const h4*)(t2f + (size_t)slab * ND128 + fidx);
        float4 o;
        o.x = fmaf((float)v[0], sS[c0 + 0], sB[c0 + 0]);
        o.y = fmaf((float)v[1], sS[c0 + 1], sB[c0 + 1]);
        o.z = fmaf((float)v[2], sS[c0 + 2], sB[c0 + 2]);
        o.w = fmaf((float)v[3], sS[c0 + 3], sB[c0 + 3]);
        *(float4*)(out + (size_t)gr * 128 + c0) = o;
    }
}

extern "C" void kernel_launch(void* const* d_in, const int* in_sizes, int n_in,
                              void* d_out, int out_size, void* d_ws, size_t ws_size,
                              hipStream_t stream)
{
    const float* h   = (const float*)d_in[0];
    const int*   src = (const int*)d_in[1];
    const int*   dst = (const int*)d_in[2];
    const float* WQ  = (const float*)d_in[3];
    const float* WK  = (const float*)d_in[4];
    const float* WV  = (const float*)d_in[5];
    const float* WO  = (const float*)d_in[6];
    const float* bO  = (const float*)d_in[7];
    const float* W1  = (const float*)d_in[8];
    const float* b1  = (const float*)d_in[9];
    const float* W2  = (const float*)d_in[10];
    const float* b2  = (const float*)d_in[11];
    const float* g1  = (const float*)d_in[12];
    const float* bb1 = (const float*)d_in[13];
    const float* g2  = (const float*)d_in[14];
    const float* bb2 = (const float*)d_in[15];
    float* out = (float*)d_out;

    int N = in_sizes[0] / 128;
    int E = in_sizes[1];
    int slabs = (N + 127) / 128;
    int nsb = (N + 2047) / 2048;               // scan blocks (~25)
    int nhb = (E + 255) / 256;                 // edge blocks (~2500)
    const size_t B1 = (size_t)slabs * 32768;   // bytes of one f16 N_pad x 128 buffer

    char* Wp = (char*)d_ws;
    f16* hb  = (f16*)Wp;                       // h f16 frags, lives through oproj
    f16* Qb  = (f16*)(Wp + B1);                // B1
    unsigned char* KV8 = (unsigned char*)(Wp + 2 * B1);  // B1 (fp8 K|V interleaved words)
    f16* attnf = (f16*)(Wp + 3 * B1);          // B1; becomes t2f after ffn2
    f16* t1b = (f16*)(Wp + 4 * B1);            // B1
    f16* ub  = (f16*)(Wp + B1);                // 2*B1, overlays Qb+KV8 after attn
    f16* t2f = attnf;                          // attnf dead after oproj
    const size_t base = 5 * B1;
    f16* Wqb = (f16*)(Wp + base);
    f16* Wkb = (f16*)(Wp + base + 32768);
    f16* Wvb = (f16*)(Wp + base + 65536);
    f16* Wob = (f16*)(Wp + base + 98304);
    f16* W1b = (f16*)(Wp + base + 131072);
    f16* W2b = (f16*)(Wp + base + 196608);
    float* badj  = (float*)(Wp + base + 262144);
    float* sfold = (float*)(Wp + base + 263168);
    float* bfold = (float*)(Wp + base + 263680);
    float* bn    = (float*)(Wp + base + 264192);     // 512 floats (memset)
    int* bsum    = (int*)(Wp + base + 266240);       // 64 ints (memset)
    int* cursor  = (int*)(Wp + base + 266496);       // N ints (memset)
    int* rowptr  = (int*)(Wp + base + 266496 + (size_t)N * 4);
    int* csr     = (int*)(Wp + base + 266496 + (size_t)N * 8 + 8);

    // zero bn(2048) + bsum(256) + cursor(N*4) in one memset
    hipMemsetAsync(Wp + base + 264192, 0, 2304 + (size_t)N * 4, stream);
    k_prep_hist<<<nhb + 6, 256, 0, stream>>>(
        WQ, WK, WV, WO, W2, Wqb, Wkb, Wvb, Wob, W2b, cursor, dst, N, E, nhb);
    k_qkvf<<<nsb + slabs, 512, 0, stream>>>(
        h, hb, Wqb, Wkb, Wvb, Qb, KV8, cursor, bsum, N, nsb);
    k_scanC<<<nsb, 256, 0, stream>>>(cursor, bsum, rowptr, cursor, N, nsb);
    k_scatter<<<nhb, 256, 0, stream>>>(src, dst, cursor, csr, E);
    k_attn<<<(N + 3) / 4, 256, 0, stream>>>(Qb, KV8, rowptr, csr, attnf, N);
    k_oproj<<<slabs, 512, 0, stream>>>(attnf, Wob, hb, bO, t1b, bn, N);
    k_fold1<<<256, 128, 0, stream>>>(bn, g1, bb1, W1, b1, W1b, badj, sfold, bfold, N);
    k_ffn1<<<slabs, 512, 0, stream>>>(t1b, W1b, badj, ub, N);
    k_ffn2<<<slabs, 512, 0, stream>>>(ub, W2b, t1b, sfold, bfold, b2, t2f, bn, N);
    k_bn2<<<(int)(((size_t)N * 32 + 255) / 256), 256, 0, stream>>>(t2f, out, bn, g2, bb2, N);
}